// Round 11
// baseline (407.723 us; speedup 1.0000x reference)
//
#include <hip/hip_runtime.h>
#include <math.h>

#define DMODEL 1024
#define NH 16
#define DHEAD 64
#define DFF 4096
#define BATCH 4
#define SEQ 2048
#define MROWS (BATCH * SEQ)   // 8192
#define LNEPS 1e-5f
#define NT (SEQ / 64)         // 32 kv tiles

typedef __attribute__((ext_vector_type(8))) short bf16x8;
typedef __attribute__((ext_vector_type(4))) float f32x4;
typedef __attribute__((ext_vector_type(16))) float f32x16;
typedef __attribute__((ext_vector_type(4))) unsigned int u32x4;

__device__ inline unsigned short f2bf(float f) {
  unsigned int u = __float_as_uint(f);
  unsigned int r = (u + 0x7fffu + ((u >> 16) & 1u)) >> 16;  // RNE
  return (unsigned short)r;
}

__device__ inline void gload16(const unsigned short* g, char* l) {
  __builtin_amdgcn_global_load_lds(
      (const __attribute__((address_space(1))) unsigned int*)g,
      (__attribute__((address_space(3))) unsigned int*)l, 16, 0, 0);
}

__device__ inline float fexp2(float x) {
  float r;
  asm("v_exp_f32 %0, %1" : "=v"(r) : "v"(x));
  return r;
}
__device__ inline unsigned int cvtpk(float lo, float hi) {
  unsigned int r;
  asm("v_cvt_pk_bf16_f32 %0, %1, %2" : "=v"(r) : "v"(lo), "v"(hi));
  return r;
}
__device__ inline void plswap(unsigned int& a, unsigned int& b) {
  asm("v_permlane32_swap_b32 %0, %1" : "+v"(a), "+v"(b));
}

// ---------------------------------------------------------------------------
// Embedding + positional encoding; dual output f32 (residual) + bf16 (GEMM A).
// ---------------------------------------------------------------------------
__global__ __launch_bounds__(256)
void embed_kernel(const int* __restrict__ tokens, const float* __restrict__ emb,
                  float* __restrict__ X, unsigned short* __restrict__ Xb) {
  const int HALF = DMODEL / 2;
  int idx = blockIdx.x * 256 + threadIdx.x;
  if (idx >= MROWS * HALF) return;
  int row = idx / HALF;
  int j = idx - row * HALF;
  int s = row & (SEQ - 1);
  int tok = tokens[row];
  float2 e = ((const float2*)(emb + (size_t)tok * DMODEL))[j];
  float denom = powf(10000.0f, (2.0f * (float)(2 * j)) / (float)DMODEL);
  float ang = (float)s / denom;
  float sn, cs;
  sincosf(ang, &sn, &cs);
  float2 o;
  o.x = e.x + sn;
  o.y = e.y + cs;
  ((float2*)(X + (size_t)row * DMODEL))[j] = o;
  ushort2 ob;
  ob.x = f2bf(o.x); ob.y = f2bf(o.y);
  ((ushort2*)(Xb + (size_t)row * DMODEL))[j] = ob;
}

// ---------------------------------------------------------------------------
// Fused fp32 -> bf16 conversion of all four weight matrices (one launch).
// ---------------------------------------------------------------------------
__global__ __launch_bounds__(256)
void cvt4_kernel(const float* __restrict__ a, const float* __restrict__ b,
                 const float* __restrict__ c, const float* __restrict__ d,
                 unsigned short* __restrict__ oa, unsigned short* __restrict__ ob,
                 unsigned short* __restrict__ oc, unsigned short* __restrict__ od) {
  int i = blockIdx.x * 256 + threadIdx.x;
  const float* src; unsigned short* dst; int off;
  if (i < 786432)       { src = a; dst = oa; off = 0; }
  else if (i < 1048576) { src = b; dst = ob; off = 786432; }
  else if (i < 2097152) { src = c; dst = oc; off = 1048576; }
  else                  { src = d; dst = od; off = 2097152; }
  int j = i - off;
  float4 v = ((const float4*)src)[j];
  ushort4 o;
  o.x = f2bf(v.x); o.y = f2bf(v.y); o.z = f2bf(v.z); o.w = f2bf(v.w);
  ((ushort4*)dst)[j] = o;
}

// ---------------------------------------------------------------------------
// gemm8p: m201-style 8-phase 256x256 GEMM (round-10 structure, unchanged).
// ---------------------------------------------------------------------------
__device__ inline void sthalf8(const unsigned short* G, int grow0, int K, int kt,
                               char* smem_, int isB, int half, int t) {
  char* dst = smem_ + ((kt & 1) * 65536) + isB * 32768 + half * 16384;
#pragma unroll
  for (int i = 0; i < 2; ++i) {
    int g = i * 512 + t;
    int r = g >> 3, sl = g & 7;
    int c = sl ^ (r & 7);
    gload16(G + (size_t)(grow0 + half * 128 + r) * K + kt * 64 + c * 8, dst + g * 16);
  }
}

#define VM4_ asm volatile("s_waitcnt vmcnt(4)" ::: "memory")
#define VM0_ asm volatile("s_waitcnt vmcnt(0)" ::: "memory")

#define PHASE8(bufofs, MG, NP, LA, LB, STAGE_STMT, WAIT_STMT)                   \
  {                                                                             \
    if (LA) {                                                                   \
      _Pragma("unroll") for (int m = 0; m < 4; ++m) {                           \
        int arow = wm * 128 + (MG) * 64 + m * 16 + fr;                          \
        _Pragma("unroll") for (int ks = 0; ks < 2; ++ks)                        \
          af[m][ks] = *(const bf16x8*)(smem + (bufofs) + arow * 128 +           \
                        (((ks * 4 + fq) ^ (arow & 7)) * 16));                   \
      }                                                                         \
    }                                                                           \
    if (LB) {                                                                   \
      _Pragma("unroll") for (int nn = 0; nn < 2; ++nn) {                        \
        int n = (NP) * 2 + nn;                                                  \
        int brow = wn * 64 + n * 16 + fr;                                       \
        _Pragma("unroll") for (int ks = 0; ks < 2; ++ks)                        \
          bf[(NP) * 2 + nn][ks] = *(const bf16x8*)(smem + (bufofs) + 32768 +    \
                        brow * 128 + (((ks * 4 + fq) ^ (brow & 7)) * 16));      \
      }                                                                         \
    }                                                                           \
    STAGE_STMT;                                                                 \
    __builtin_amdgcn_sched_barrier(0);                                          \
    __builtin_amdgcn_s_barrier();                                               \
    asm volatile("s_waitcnt lgkmcnt(0)" ::: "memory");                          \
    __builtin_amdgcn_sched_barrier(0);                                          \
    __builtin_amdgcn_s_setprio(1);                                              \
    _Pragma("unroll") for (int m = 0; m < 4; ++m)                               \
      _Pragma("unroll") for (int nn = 0; nn < 2; ++nn)                          \
        _Pragma("unroll") for (int ks = 0; ks < 2; ++ks)                        \
          acc[(MG) * 4 + m][(NP) * 2 + nn] =                                    \
              __builtin_amdgcn_mfma_f32_16x16x32_bf16(                          \
                  af[m][ks], bf[(NP) * 2 + nn][ks],                             \
                  acc[(MG) * 4 + m][(NP) * 2 + nn], 0, 0, 0);                   \
    __builtin_amdgcn_s_setprio(0);                                              \
    WAIT_STMT;                                                                  \
    __builtin_amdgcn_sched_barrier(0);                                          \
    __builtin_amdgcn_s_barrier();                                               \
    __builtin_amdgcn_sched_barrier(0);                                          \
  }

__global__ __launch_bounds__(512, 2)
void gemm8p(const unsigned short* __restrict__ A, const unsigned short* __restrict__ B,
            const float* __restrict__ bias, const float* __restrict__ resid,
            float* __restrict__ Cf, unsigned short* __restrict__ Cb,
            int M, int N, int K, int relu) {
  extern __shared__ char smem[];   // 131072: 2 bufs x (A 32K + B 32K)

  const int t = threadIdx.x;
  const int lane = t & 63;
  const int wv = t >> 6;
  const int wm = wv >> 2;
  const int wn = wv & 3;
  const int fr = lane & 15;
  const int fq = lane >> 4;

  const int nwg = gridDim.x;
  const int orig = blockIdx.x;
  const int q8 = nwg >> 3;
  const int wgid = (orig & 7) * q8 + (orig >> 3);
  const int stid = wgid >> 2, within = wgid & 3;
  const int sm = within & 1, sn = within >> 1;
  const int Msup = M >> 9;
  const int stm = stid % Msup, stn = stid / Msup;
  const int m0 = (stm * 2 + sm) * 256;
  const int n0 = (stn * 2 + sn) * 256;

  f32x4 acc[8][4];
#pragma unroll
  for (int m = 0; m < 8; ++m)
#pragma unroll
    for (int n = 0; n < 4; ++n) acc[m][n] = (f32x4){0.f, 0.f, 0.f, 0.f};

  const int nk = K / 64;
  const int nj = nk / 2;

  sthalf8(A, m0, K, 0, smem, 0, 0, t);
  sthalf8(A, m0, K, 0, smem, 0, 1, t);
  sthalf8(B, n0, K, 0, smem, 1, 0, t);
  sthalf8(B, n0, K, 0, smem, 1, 1, t);
  sthalf8(B, n0, K, 1, smem, 1, 0, t);
  sthalf8(B, n0, K, 1, smem, 1, 1, t);
  VM4_;
  __builtin_amdgcn_sched_barrier(0);
  __builtin_amdgcn_s_barrier();
  __builtin_amdgcn_sched_barrier(0);

  bf16x8 af[4][2];
  bf16x8 bf[4][2];

  for (int j = 0; j < nj; ++j) {
    const bool st = (j + 1 < nj);
    PHASE8(0, 0, 0, 1, 1, sthalf8(A, m0, K, 2 * j + 1, smem, 0, 0, t), );
    PHASE8(0, 0, 1, 0, 1, sthalf8(A, m0, K, 2 * j + 1, smem, 0, 1, t), );
    PHASE8(0, 1, 1, 1, 0,
           if (st) sthalf8(B, n0, K, 2 * j + 2, smem, 1, 0, t), );
    PHASE8(0, 1, 0, 0, 0,
           if (st) sthalf8(B, n0, K, 2 * j + 2, smem, 1, 1, t),
           { if (st) { VM4_; } else { VM0_; } });
    PHASE8(65536, 0, 0, 1, 1,
           if (st) sthalf8(A, m0, K, 2 * j + 2, smem, 0, 0, t), );
    PHASE8(65536, 0, 1, 0, 1,
           if (st) sthalf8(A, m0, K, 2 * j + 2, smem, 0, 1, t), );
    PHASE8(65536, 1, 1, 1, 0,
           if (st) sthalf8(B, n0, K, 2 * j + 3, smem, 1, 0, t), );
    PHASE8(65536, 1, 0, 0, 0,
           if (st) sthalf8(B, n0, K, 2 * j + 3, smem, 1, 1, t),
           { if (st) { VM4_; } });
  }

  float* slab = (float*)(smem + wv * 4352);
#pragma unroll
  for (int m = 0; m < 8; ++m) {
#pragma unroll
    for (int n = 0; n < 4; ++n)
#pragma unroll
      for (int j = 0; j < 4; ++j)
        slab[(fq * 4 + j) * 68 + n * 16 + fr] = acc[m][n][j];
    int rg0 = m0 + wm * 128 + m * 16;
#pragma unroll
    for (int it = 0; it < 4; ++it) {
      int u = it * 64 + lane;
      int row = u >> 4, seg = u & 15;
      float4 v = *(const float4*)&slab[row * 68 + seg * 4];
      int col = n0 + wn * 64 + seg * 4;
      float4 b4 = *(const float4*)&bias[col];
      v.x += b4.x; v.y += b4.y; v.z += b4.z; v.w += b4.w;
      if (relu) {
        v.x = fmaxf(v.x, 0.f); v.y = fmaxf(v.y, 0.f);
        v.z = fmaxf(v.z, 0.f); v.w = fmaxf(v.w, 0.f);
      }
      size_t idx = (size_t)(rg0 + row) * N + col;
      if (resid) {
        float4 r4 = *(const float4*)&resid[idx];
        v.x += r4.x; v.y += r4.y; v.z += r4.z; v.w += r4.w;
      }
      if (Cf) {
        *(float4*)&Cf[idx] = v;
      } else {
        ushort4 ob;
        ob.x = f2bf(v.x); ob.y = f2bf(v.y); ob.z = f2bf(v.z); ob.w = f2bf(v.w);
        *(ushort4*)&Cb[idx] = ob;
      }
    }
  }
}

// ---------------------------------------------------------------------------
// bf16 MFMA GEMM, BM=256 BN=128 (round-7 structure; N=1024 shapes).
// ---------------------------------------------------------------------------
#define AOFF(buf) ((buf) * 49152)
#define BOFF(buf) ((buf) * 49152 + 32768)

__device__ inline void stageA(const unsigned short* Ag, char* smem_, int buf,
                              int m0, int K, int kt, int wv, int lane) {
  int rl = lane >> 3, c = (lane & 7) ^ rl;
#pragma unroll
  for (int i = 0; i < 4; ++i) {
    int r0 = (wv * 4 + i) * 8;
    gload16(Ag + (size_t)(m0 + r0 + rl) * K + kt * 64 + c * 8,
            smem_ + AOFF(buf) + r0 * 128 + lane * 16);
  }
}
__device__ inline void stageB2(const unsigned short* Bg, char* smem_, int buf,
                               int n0, int K, int kt, int wv, int lane) {
  int rl = lane >> 3, c = (lane & 7) ^ rl;
#pragma unroll
  for (int i = 0; i < 2; ++i) {
    int r0 = (wv * 2 + i) * 8;
    gload16(Bg + (size_t)(n0 + r0 + rl) * K + kt * 64 + c * 8,
            smem_ + BOFF(buf) + r0 * 128 + lane * 16);
  }
}

#define VM6 asm volatile("s_waitcnt vmcnt(6)" ::: "memory")
#define VM0 asm volatile("s_waitcnt vmcnt(0)" ::: "memory")

#define DO_PHASE(buf, mb, LOADB, STAGE_STMT, WAIT_STMT)                         \
  {                                                                             \
    bf16x8 af[2][2];                                                            \
    _Pragma("unroll") for (int mm = 0; mm < 2; ++mm) {                          \
      int arow = wm * 64 + ((mb) + mm) * 16 + fr;                               \
      _Pragma("unroll") for (int ks = 0; ks < 2; ++ks) {                        \
        int slot = (ks * 4 + fq) ^ (arow & 7);                                  \
        af[mm][ks] = *(const bf16x8*)(smem + AOFF(buf) + arow * 128 + slot * 16); \
      }                                                                         \
    }                                                                           \
    if (LOADB) {                                                                \
      _Pragma("unroll") for (int n = 0; n < 4; ++n) {                           \
        int brow = wn * 64 + n * 16 + fr;                                       \
        _Pragma("unroll") for (int ks = 0; ks < 2; ++ks) {                      \
          int slot = (ks * 4 + fq) ^ (brow & 7);                                \
          bfr[n][ks] = *(const bf16x8*)(smem + BOFF(buf) + brow * 128 + slot * 16); \
        }                                                                       \
      }                                                                         \
    }                                                                           \
    STAGE_STMT;                                                                 \
    __builtin_amdgcn_sched_barrier(0);                                          \
    __builtin_amdgcn_s_barrier();                                               \
    __builtin_amdgcn_sched_barrier(0);                                          \
    __builtin_amdgcn_s_setprio(1);                                              \
    _Pragma("unroll") for (int mm = 0; mm < 2; ++mm)                            \
      _Pragma("unroll") for (int n = 0; n < 4; ++n)                             \
        _Pragma("unroll") for (int ks = 0; ks < 2; ++ks)                        \
          acc[(mb) + mm][n] = __builtin_amdgcn_mfma_f32_16x16x32_bf16(          \
              af[mm][ks], bfr[n][ks], acc[(mb) + mm][n], 0, 0, 0);              \
    __builtin_amdgcn_s_setprio(0);                                              \
    WAIT_STMT;                                                                  \
    __builtin_amdgcn_sched_barrier(0);                                          \
    __builtin_amdgcn_s_barrier();                                               \
    __builtin_amdgcn_sched_barrier(0);                                          \
  }

__global__ __launch_bounds__(512, 2)
void gemm8(const unsigned short* __restrict__ A, const unsigned short* __restrict__ B,
           const float* __restrict__ bias, const float* __restrict__ resid,
           float* __restrict__ Cf, unsigned short* __restrict__ Cb,
           int M, int N, int K, int relu) {
  extern __shared__ char smem[];   // 144 KB: 3 bufs x (A 32K + B 16K)

  const int t = threadIdx.x;
  const int lane = t & 63;
  const int wv = t >> 6;
  const int wm = wv >> 1;
  const int wn = wv & 1;
  const int fr = lane & 15;
  const int fq = lane >> 4;

  const int nwg = gridDim.x;
  const int orig = blockIdx.x;
  const int q8 = nwg >> 3;
  const int wgid = (orig & 7) * q8 + (orig >> 3);
  const int stid = wgid >> 4, within = wgid & 15;
  const int sm = within & 3, sn = within >> 2;
  const int Msup = M >> 10;
  const int stm = stid % Msup, stn = stid / Msup;
  const int m0 = (stm * 4 + sm) * 256;
  const int n0 = (stn * 4 + sn) * 128;

  f32x4 acc[4][4];
#pragma unroll
  for (int m = 0; m < 4; ++m)
#pragma unroll
    for (int n = 0; n < 4; ++n) acc[m][n] = (f32x4){0.f, 0.f, 0.f, 0.f};

  const int nk = K / 64;
  const int nj = nk / 2;

  stageB2(B, smem, 0, n0, K, 0, wv, lane);
  stageA (A, smem, 0, m0, K, 0, wv, lane);
  stageB2(B, smem, 1, n0, K, 1, wv, lane);
  stageA (A, smem, 1, m0, K, 1, wv, lane);
  VM6;
  __builtin_amdgcn_sched_barrier(0);
  __builtin_amdgcn_s_barrier();
  __builtin_amdgcn_sched_barrier(0);

  for (int j = 0; j < nj - 1; ++j) {
    const int k0 = 2 * j, k1 = 2 * j + 1;
    const int s0k = k0 + 2, s1k = k1 + 2;
    const int b0 = k0 % 3, b1 = k1 % 3;
    const int sb0 = s0k % 3, sb1 = s1k % 3;
    bf16x8 bfr[4][2];
    DO_PHASE(b0, 0, true,  stageB2(B, smem, sb0, n0, K, s0k, wv, lane), );
    DO_PHASE(b0, 2, false, stageA (A, smem, sb0, m0, K, s0k, wv, lane), VM6);
    DO_PHASE(b1, 0, true,  stageB2(B, smem, sb1, n0, K, s1k, wv, lane), );
    DO_PHASE(b1, 2, false, stageA (A, smem, sb1, m0, K, s1k, wv, lane), VM6);
  }
  {
    const int b0 = (nk - 2) % 3, b1 = (nk - 1) % 3;
    bf16x8 bfr[4][2];
    DO_PHASE(b0, 0, true,  , );
    DO_PHASE(b0, 2, false, , VM0);
    DO_PHASE(b1, 0, true,  , );
    DO_PHASE(b1, 2, false, , );
  }

  float* slab = (float*)(smem + wv * 4352);
#pragma unroll
  for (int m = 0; m < 4; ++m) {
#pragma unroll
    for (int n = 0; n < 4; ++n)
#pragma unroll
      for (int j = 0; j < 4; ++j)
        slab[(fq * 4 + j) * 68 + n * 16 + fr] = acc[m][n][j];
    int rg0 = m0 + wm * 64 + m * 16;
#pragma unroll
    for (int it = 0; it < 4; ++it) {
      int u = it * 64 + lane;
      int row = u >> 4, seg = u & 15;
      float4 v = *(const float4*)&slab[row * 68 + seg * 4];
      int col = n0 + wn * 64 + seg * 4;
      float4 b4 = *(const float4*)&bias[col];
      v.x += b4.x; v.y += b4.y; v.z += b4.z; v.w += b4.w;
      if (relu) {
        v.x = fmaxf(v.x, 0.f); v.y = fmaxf(v.y, 0.f);
        v.z = fmaxf(v.z, 0.f); v.w = fmaxf(v.w, 0.f);
      }
      size_t idx = (size_t)(rg0 + row) * N + col;
      if (resid) {
        float4 r4 = *(const float4*)&resid[idx];
        v.x += r4.x; v.y += r4.y; v.z += r4.z; v.w += r4.w;
      }
      if (Cf) {
        *(float4*)&Cf[idx] = v;
      } else {
        ushort4 ob;
        ob.x = f2bf(v.x); ob.y = f2bf(v.y); ob.z = f2bf(v.z); ob.w = f2bf(v.w);
        *(ushort4*)&Cb[idx] = ob;
      }
    }
  }
}

// ---------------------------------------------------------------------------
// V transpose: qkvb V-part -> vtb [(bh*64 + d)][s].
// ---------------------------------------------------------------------------
__global__ __launch_bounds__(256)
void vtrans_kernel(const unsigned short* __restrict__ qkvb, unsigned short* __restrict__ vtb) {
  __shared__ __align__(16) unsigned short tile[64][64];
  const int st = blockIdx.x;
  const int bh = blockIdx.y;
  const int b = bh >> 4, h = bh & 15;
  const int t = threadIdx.x;
#pragma unroll
  for (int p = 0; p < 2; ++p) {
    int item = p * 256 + t;
    int r = item >> 3, c8 = item & 7;
    const unsigned short* src =
        qkvb + (size_t)(b * SEQ + st * 64 + r) * (3 * DMODEL) + 2048 + h * 64 + c8 * 8;
    *(uint4*)&tile[r][(c8 ^ (r & 7)) * 8] = *(const uint4*)src;
  }
  __syncthreads();
#pragma unroll
  for (int p = 0; p < 2; ++p) {
    int item = p * 256 + t;
    int d = item & 63, s8 = item >> 6;
    unsigned short v[8];
#pragma unroll
    for (int e = 0; e < 8; ++e) {
      int s = s8 * 8 + e;
      v[e] = tile[s][(((d >> 3) ^ (s & 7)) * 8) + (d & 7)];
    }
    uint4 u;
    u.x = (unsigned int)v[0] | ((unsigned int)v[1] << 16);
    u.y = (unsigned int)v[2] | ((unsigned int)v[3] << 16);
    u.z = (unsigned int)v[4] | ((unsigned int)v[5] << 16);
    u.w = (unsigned int)v[6] | ((unsigned int)v[7] << 16);
    *(uint4*)(vtb + ((size_t)bh * 64 + d) * SEQ + st * 64 + s8 * 8) = u;
  }
}

// ---------------------------------------------------------------------------
// MFMA flash attention v6: v5 structure with 64 q-rows per wave — each K/V
// LDS fragment read feeds TWO MFMAs (qf0/qf1 and pa0/pa1), halving per-CU
// LDS read volume (the measured v5 bottleneck). Block = 512 q-rows, 8 waves,
// grid = 256 = 1 block/CU. Staging, swizzles, pack path unchanged (proven).
// All register arrays statically indexed (rule 20).
// ---------------------------------------------------------------------------
__global__ __launch_bounds__(512, 2)
void attn_kernel(const unsigned short* __restrict__ qkv, const unsigned short* __restrict__ vtb,
                 unsigned short* __restrict__ ctxb) {
  __shared__ __align__(16) unsigned short Ks[2][64][64];
  __shared__ __align__(16) unsigned short Vts[2][64][64];
  __shared__ __align__(16) unsigned short Slab[8][32][64];

  const int t = threadIdx.x;
  const int lane = t & 63;
  const int wq = t >> 6;            // wave: q-rows [q0 + wq*64, +64)
  const int l31 = lane & 31;
  const int hi1 = lane >> 5;
  const int bid = blockIdx.x;
  const int bh = bid & 63;          // bh fastest -> same-bh blocks share XCD
  const int qt = bid >> 6;          // 0..3
  const int b = bh >> 4, h = bh & 15;
  const int q0 = qt * 512;

  const size_t RS = 3 * DMODEL;
  const unsigned short* qb = qkv + (size_t)b * SEQ * RS + h * DHEAD;
  const unsigned short* kb = qb + DMODEL;

  // Q fragments for both 32-row subtiles (B-operand): col=q=l31, k=s*16+hi1*8
  bf16x8 qf0[4], qf1[4];
  {
    const unsigned short* qr0 = qb + (size_t)(q0 + wq * 64 + l31) * RS;
    const unsigned short* qr1 = qr0 + 32 * RS;
#pragma unroll
    for (int s = 0; s < 4; ++s) {
      qf0[s] = *(const bf16x8*)(qr0 + s * 16 + hi1 * 8);
      qf1[s] = *(const bf16x8*)(qr1 + s * 16 + hi1 * 8);
    }
  }

  const unsigned short* kgl =
      kb + (size_t)(wq * 8 + (lane >> 3)) * RS + ((lane & 7) ^ (lane >> 3)) * 8;
  const unsigned short* vgl =
      vtb + ((size_t)bh * 64 + wq * 8 + (lane >> 3)) * SEQ + ((lane & 7) ^ (lane >> 3)) * 8;

  f32x16 oacc0[2] = {};
  f32x16 oacc1[2] = {};
  float lacc0 = 0.f, lacc1 = 0.f;

  gload16(kgl, (char*)&Ks[0][wq * 8][0]);
  gload16(vgl, (char*)&Vts[0][wq * 8][0]);
  __syncthreads();

  const float C = 0.18033688011112042f;   // 0.125 * log2(e)

  for (int kt = 0; kt < NT; ++kt) {
    const int cur = kt & 1;
    if (kt + 1 < NT) {
      gload16(kgl + (size_t)(kt + 1) * 64 * RS, (char*)&Ks[cur ^ 1][wq * 8][0]);
      gload16(vgl + (size_t)(kt + 1) * 64, (char*)&Vts[cur ^ 1][wq * 8][0]);
    }

    // QK^T for both q-subtiles: each kf read feeds 2 MFMAs
    f32x16 sacc0[2] = {};
    f32x16 sacc1[2] = {};
    __builtin_amdgcn_s_setprio(1);
#pragma unroll
    for (int s = 0; s < 4; ++s) {
#pragma unroll
      for (int kvt = 0; kvt < 2; ++kvt) {
        int row = kvt * 32 + l31;
        bf16x8 kf = *(const bf16x8*)&Ks[cur][row][(((2 * s + hi1) ^ (row & 7)) * 8)];
        sacc0[kvt] = __builtin_amdgcn_mfma_f32_32x32x16_bf16(kf, qf0[s], sacc0[kvt], 0, 0, 0);
        sacc1[kvt] = __builtin_amdgcn_mfma_f32_32x32x16_bf16(kf, qf1[s], sacc1[kvt], 0, 0, 0);
      }
    }
    __builtin_amdgcn_s_setprio(0);

    // exp + pack, both subtiles -> pa0[4], pa1[4] (k-step s2 = kvt*2+half)
    bf16x8 pa0[4], pa1[4];
#pragma unroll
    for (int kvt = 0; kvt < 2; ++kvt) {
      float p0[16], p1[16];
#pragma unroll
      for (int r = 0; r < 16; ++r) p0[r] = fexp2(sacc0[kvt][r] * C);
#pragma unroll
      for (int r = 0; r < 16; ++r) p1[r] = fexp2(sacc1[kvt][r] * C);
      float ps0 = 0.f, ps1 = 0.f;
#pragma unroll
      for (int r = 0; r < 16; ++r) { ps0 += p0[r]; ps1 += p1[r]; }
      lacc0 += ps0;
      lacc1 += ps1;
#pragma unroll
      for (int half = 0; half < 2; ++half) {
        const int lo = half * 8;
        {
          unsigned int x0 = cvtpk(p0[lo + 0], p0[lo + 1]);
          unsigned int x1 = cvtpk(p0[lo + 2], p0[lo + 3]);
          unsigned int y0 = cvtpk(p0[lo + 4], p0[lo + 5]);
          unsigned int y1 = cvtpk(p0[lo + 6], p0[lo + 7]);
          plswap(x0, y0);
          plswap(x1, y1);
          pa0[kvt * 2 + half] = __builtin_bit_cast(bf16x8, (u32x4){x0, x1, y0, y1});
        }
        {
          unsigned int x0 = cvtpk(p1[lo + 0], p1[lo + 1]);
          unsigned int x1 = cvtpk(p1[lo + 2], p1[lo + 3]);
          unsigned int y0 = cvtpk(p1[lo + 4], p1[lo + 5]);
          unsigned int y1 = cvtpk(p1[lo + 6], p1[lo + 7]);
          plswap(x0, y0);
          plswap(x1, y1);
          pa1[kvt * 2 + half] = __builtin_bit_cast(bf16x8, (u32x4){x0, x1, y0, y1});
        }
      }
    }

    // PV: each vf read feeds 2 MFMAs
    __builtin_amdgcn_s_setprio(1);
#pragma unroll
    for (int s2 = 0; s2 < 4; ++s2) {
#pragma unroll
      for (int dt = 0; dt < 2; ++dt) {
        int vrow = dt * 32 + l31;
        bf16x8 vf = *(const bf16x8*)&Vts[cur][vrow][(((2 * s2 + hi1) ^ (vrow & 7)) * 8)];
        oacc0[dt] = __builtin_amdgcn_mfma_f32_32x32x16_bf16(pa0[s2], vf, oacc0[dt], 0, 0, 0);
        oacc1[dt] = __builtin_amdgcn_mfma_f32_32x32x16_bf16(pa1[s2], vf, oacc1[dt], 0, 0, 0);
      }
    }
    __builtin_amdgcn_s_setprio(0);
    __syncthreads();
  }

  // epilogue: per-subtile normalize + pack via wave-private Slab (2 passes)
  lacc0 += __shfl_xor(lacc0, 32);
  lacc1 += __shfl_xor(lacc1, 32);
  float inv0 = 1.0f / lacc0;
  float inv1 = 1.0f / lacc1;

  float iv0[16], iv1[16];
#pragma unroll
  for (int r = 0; r < 16; ++r) {
    int qp = (r & 3) + 8 * (r >> 2) + 4 * hi1;
    iv0[r] = __shfl(inv0, qp);
    iv1[r] = __shfl(inv1, qp);
  }

#pragma unroll
  for (int qi = 0; qi < 2; ++qi) {
#pragma unroll
    for (int dt = 0; dt < 2; ++dt) {
      const int chunk = dt * 4 + (l31 >> 3);
      const int e7 = l31 & 7;
#pragma unroll
      for (int r = 0; r < 16; ++r) {
        int qp = (r & 3) + 8 * (r >> 2) + 4 * hi1;
        float val = (qi == 0) ? oacc0[dt][r] * iv0[r] : oacc1[dt][r] * iv1[r];
        Slab[wq][qp][((chunk ^ (qp & 7)) * 8) + e7] = f2bf(val);
      }
    }
#pragma unroll
    for (int it = 0; it < 4; ++it) {
      int u = it * 64 + lane;
      int row = u >> 3, s = u & 7;
      uint4 v = *(const uint4*)&Slab[wq][row][((s ^ (row & 7)) * 8)];
      *(uint4*)(ctxb + (size_t)(b * SEQ + q0 + wq * 64 + qi * 32 + row) * DMODEL +
                h * DHEAD + s * 8) = v;
    }
  }
}

// ---------------------------------------------------------------------------
// LayerNorm with optional secondary bf16 output.
// ---------------------------------------------------------------------------
__global__ __launch_bounds__(256)
void ln_kernel(const float* __restrict__ Z, const float* __restrict__ g,
               const float* __restrict__ bta, float* __restrict__ Y,
               unsigned short* __restrict__ Yb) {
  const int row = blockIdx.x;
  const float4* z4 = (const float4*)(Z + (size_t)row * DMODEL);
  float4 v = z4[threadIdx.x];
  float s = v.x + v.y + v.z + v.w;
  float ss = fmaf(v.x, v.x, fmaf(v.y, v.y, fmaf(v.z, v.z, v.w * v.w)));
#pragma unroll
  for (int o = 32; o >= 1; o >>= 1) {
    s += __shfl_xor(s, o);
    ss += __shfl_xor(ss, o);
  }
  __shared__ float red[8];
  int w = threadIdx.x >> 6;
  if ((threadIdx.x & 63) == 0) { red[w] = s; red[4 + w] = ss; }
  __syncthreads();
  s = red[0] + red[1] + red[2] + red[3];
  ss = red[4] + red[5] + red[6] + red[7];
  float mu = s * (1.0f / DMODEL);
  float var = ss * (1.0f / DMODEL) - mu * mu;
  float rs = rsqrtf(var + LNEPS);
  float4 gg = ((const float4*)g)[threadIdx.x];
  float4 bb = ((const float4*)bta)[threadIdx.x];
  float4 o;
  o.x = (v.x - mu) * rs * gg.x + bb.x;
  o.y = (v.y - mu) * rs * gg.y + bb.y;
  o.z = (v.z - mu) * rs * gg.z + bb.z;
  o.w = (v.w - mu) * rs * gg.w + bb.w;
  ((float4*)(Y + (size_t)row * DMODEL))[threadIdx.x] = o;
  if (Yb) {
    ushort4 ob;
    ob.x = f2bf(o.x); ob.y = f2bf(o.y); ob.z = f2bf(o.z); ob.w = f2bf(o.w);
    ((ushort4*)(Yb + (size_t)row * DMODEL))[threadIdx.x] = ob;
  }
}

// ---------------------------------------------------------------------------
extern "C" void kernel_launch(void* const* d_in, const int* in_sizes, int n_in,
                              void* d_out, int out_size, void* d_ws, size_t ws_size,
                              hipStream_t stream) {
  const int* tokens       = (const int*)d_in[0];
  const float* emb        = (const float*)d_in[1];
  const float* in_proj_w  = (const float*)d_in[2];
  const float* in_proj_b  = (const float*)d_in[3];
  const float* out_proj_w = (const float*)d_in[4];
  const float* out_proj_b = (const float*)d_in[5];
  const float* w1         = (const float*)d_in[6];
  const float* b1         = (const float*)d_in[7];
  const float* w2         = (const float*)d_in[8];
  const float* b2         = (const float*)d_in[9];
  const float* g1         = (const float*)d_in[10];
  const float* beta1      = (const float*)d_in[11];
  const float* g2         = (const float*)d_in[12];
  const float* beta2      = (const float*)d_in[13];
  float* out = (float*)d_out;

  char* ws = (char*)d_ws;
  const size_t MB = 1ull << 20;
  unsigned short* inwb  = (unsigned short*)(ws + 0 * MB);
  unsigned short* outwb = (unsigned short*)(ws + 6 * MB);
  unsigned short* w1b   = (unsigned short*)(ws + 8 * MB);
  unsigned short* w2b   = (unsigned short*)(ws + 16 * MB);
  float* x              = (float*)(ws + 24 * MB);
  unsigned short* xb    = (unsigned short*)(ws + 56 * MB);
  unsigned short* qkvb  = (unsigned short*)(ws + 72 * MB);
  unsigned short* vtb   = (unsigned short*)(ws + 120 * MB);
  unsigned short* ctxb  = (unsigned short*)(ws + 56 * MB);
  float* h              = (float*)(ws + 72 * MB);
  unsigned short* hb    = (unsigned short*)(ws + 104 * MB);
  unsigned short* ffbb  = (unsigned short*)(ws + 120 * MB);
  float* y2             = (float*)(ws + 24 * MB);

  const size_t GLDS8 = 147456;    // gemm8: 144 KB
  const size_t GLDSP = 131072;    // gemm8p: 128 KB

  embed_kernel<<<(MROWS * (DMODEL / 2) + 255) / 256, 256, 0, stream>>>(tokens, emb, x, xb);
  cvt4_kernel<<<12288, 256, 0, stream>>>(in_proj_w, out_proj_w, w1, w2,
                                         inwb, outwb, w1b, w2b);
  // qkv = x @ in_proj_w^T + b  (bf16 out)   [384 blocks, 8-phase]
  gemm8p<<<(MROWS / 256) * (3 * DMODEL / 256), 512, GLDSP, stream>>>(
      xb, inwb, in_proj_b, nullptr, nullptr, qkvb, MROWS, 3 * DMODEL, DMODEL, 0);
  // V^T pre-transpose
  vtrans_kernel<<<dim3(SEQ / 64, BATCH * NH), 256, 0, stream>>>(qkvb, vtb);
  // flash attention v6 -> ctxb (bf16)   [256 blocks, 512 q-rows each]
  attn_kernel<<<(SEQ / 512) * (BATCH * NH), 512, 0, stream>>>(qkvb, vtb, ctxb);
  // h = ctx @ out_proj_w^T + b + x  (f32 out)   [256 blocks]
  gemm8<<<(MROWS / 256) * (DMODEL / 128), 512, GLDS8, stream>>>(
      ctxb, outwb, out_proj_b, x, h, nullptr, MROWS, DMODEL, DMODEL, 0);
  ln_kernel<<<MROWS, 256, 0, stream>>>(h, g1, beta1, h, hb);
  // ffb = relu(h @ w1^T + b1)  (bf16 out)   [512 blocks, 8-phase]
  gemm8p<<<(MROWS / 256) * (DFF / 256), 512, GLDSP, stream>>>(
      hb, w1b, b1, nullptr, nullptr, ffbb, MROWS, DFF, DMODEL, 1);
  // y2 = ffb @ w2^T + b2 + h  (f32 out)   [256 blocks]
  gemm8<<<(MROWS / 256) * (DMODEL / 128), 512, GLDS8, stream>>>(
      ffbb, w2b, b2, h, y2, nullptr, MROWS, DMODEL, DFF, 0);
  ln_kernel<<<MROWS, 256, 0, stream>>>(y2, g2, beta2, out, nullptr);
}

// Round 12
// 401.103 us; speedup vs baseline: 1.0165x; 1.0165x over previous
//
#include <hip/hip_runtime.h>
#include <math.h>

#define DMODEL 1024
#define NH 16
#define DHEAD 64
#define DFF 4096
#define BATCH 4
#define SEQ 2048
#define MROWS (BATCH * SEQ)   // 8192
#define LNEPS 1e-5f
#define NT (SEQ / 64)         // 32 kv tiles

typedef __attribute__((ext_vector_type(8))) short bf16x8;
typedef __attribute__((ext_vector_type(4))) float f32x4;
typedef __attribute__((ext_vector_type(16))) float f32x16;
typedef __attribute__((ext_vector_type(4))) unsigned int u32x4;

__device__ inline unsigned short f2bf(float f) {
  unsigned int u = __float_as_uint(f);
  unsigned int r = (u + 0x7fffu + ((u >> 16) & 1u)) >> 16;  // RNE
  return (unsigned short)r;
}

__device__ inline void gload16(const unsigned short* g, char* l) {
  __builtin_amdgcn_global_load_lds(
      (const __attribute__((address_space(1))) unsigned int*)g,
      (__attribute__((address_space(3))) unsigned int*)l, 16, 0, 0);
}

__device__ inline float fexp2(float x) {
  float r;
  asm("v_exp_f32 %0, %1" : "=v"(r) : "v"(x));
  return r;
}
__device__ inline unsigned int cvtpk(float lo, float hi) {
  unsigned int r;
  asm("v_cvt_pk_bf16_f32 %0, %1, %2" : "=v"(r) : "v"(lo), "v"(hi));
  return r;
}
__device__ inline void plswap(unsigned int& a, unsigned int& b) {
  asm("v_permlane32_swap_b32 %0, %1" : "+v"(a), "+v"(b));
}

// ---------------------------------------------------------------------------
// Embedding + positional encoding; dual output f32 (residual) + bf16 (GEMM A).
// ---------------------------------------------------------------------------
__global__ __launch_bounds__(256)
void embed_kernel(const int* __restrict__ tokens, const float* __restrict__ emb,
                  float* __restrict__ X, unsigned short* __restrict__ Xb) {
  const int HALF = DMODEL / 2;
  int idx = blockIdx.x * 256 + threadIdx.x;
  if (idx >= MROWS * HALF) return;
  int row = idx / HALF;
  int j = idx - row * HALF;
  int s = row & (SEQ - 1);
  int tok = tokens[row];
  float2 e = ((const float2*)(emb + (size_t)tok * DMODEL))[j];
  float denom = powf(10000.0f, (2.0f * (float)(2 * j)) / (float)DMODEL);
  float ang = (float)s / denom;
  float sn, cs;
  sincosf(ang, &sn, &cs);
  float2 o;
  o.x = e.x + sn;
  o.y = e.y + cs;
  ((float2*)(X + (size_t)row * DMODEL))[j] = o;
  ushort2 ob;
  ob.x = f2bf(o.x); ob.y = f2bf(o.y);
  ((ushort2*)(Xb + (size_t)row * DMODEL))[j] = ob;
}

// ---------------------------------------------------------------------------
// Fused fp32 -> bf16 conversion of all four weight matrices (one launch).
// ---------------------------------------------------------------------------
__global__ __launch_bounds__(256)
void cvt4_kernel(const float* __restrict__ a, const float* __restrict__ b,
                 const float* __restrict__ c, const float* __restrict__ d,
                 unsigned short* __restrict__ oa, unsigned short* __restrict__ ob,
                 unsigned short* __restrict__ oc, unsigned short* __restrict__ od) {
  int i = blockIdx.x * 256 + threadIdx.x;
  const float* src; unsigned short* dst; int off;
  if (i < 786432)       { src = a; dst = oa; off = 0; }
  else if (i < 1048576) { src = b; dst = ob; off = 786432; }
  else if (i < 2097152) { src = c; dst = oc; off = 1048576; }
  else                  { src = d; dst = od; off = 2097152; }
  int j = i - off;
  float4 v = ((const float4*)src)[j];
  ushort4 o;
  o.x = f2bf(v.x); o.y = f2bf(v.y); o.z = f2bf(v.z); o.w = f2bf(v.w);
  ((ushort4*)dst)[j] = o;
}

// ---------------------------------------------------------------------------
// gemm8p: m201-style 8-phase 256x256 GEMM (round-10 structure, unchanged;
// used for qkv and ff1).
// ---------------------------------------------------------------------------
__device__ inline void sthalf8(const unsigned short* G, int grow0, int K, int kt,
                               char* smem_, int isB, int half, int t) {
  char* dst = smem_ + ((kt & 1) * 65536) + isB * 32768 + half * 16384;
#pragma unroll
  for (int i = 0; i < 2; ++i) {
    int g = i * 512 + t;
    int r = g >> 3, sl = g & 7;
    int c = sl ^ (r & 7);
    gload16(G + (size_t)(grow0 + half * 128 + r) * K + kt * 64 + c * 8, dst + g * 16);
  }
}

#define VM4_ asm volatile("s_waitcnt vmcnt(4)" ::: "memory")
#define VM2_ asm volatile("s_waitcnt vmcnt(2)" ::: "memory")
#define VM0_ asm volatile("s_waitcnt vmcnt(0)" ::: "memory")

#define PHASE8(bufofs, MG, NP, LA, LB, STAGE_STMT, WAIT_STMT)                   \
  {                                                                             \
    if (LA) {                                                                   \
      _Pragma("unroll") for (int m = 0; m < 4; ++m) {                           \
        int arow = wm * 128 + (MG) * 64 + m * 16 + fr;                          \
        _Pragma("unroll") for (int ks = 0; ks < 2; ++ks)                        \
          af[m][ks] = *(const bf16x8*)(smem + (bufofs) + arow * 128 +           \
                        (((ks * 4 + fq) ^ (arow & 7)) * 16));                   \
      }                                                                         \
    }                                                                           \
    if (LB) {                                                                   \
      _Pragma("unroll") for (int nn = 0; nn < 2; ++nn) {                        \
        int n = (NP) * 2 + nn;                                                  \
        int brow = wn * 64 + n * 16 + fr;                                       \
        _Pragma("unroll") for (int ks = 0; ks < 2; ++ks)                        \
          bf[(NP) * 2 + nn][ks] = *(const bf16x8*)(smem + (bufofs) + 32768 +    \
                        brow * 128 + (((ks * 4 + fq) ^ (brow & 7)) * 16));      \
      }                                                                         \
    }                                                                           \
    STAGE_STMT;                                                                 \
    __builtin_amdgcn_sched_barrier(0);                                          \
    __builtin_amdgcn_s_barrier();                                               \
    asm volatile("s_waitcnt lgkmcnt(0)" ::: "memory");                          \
    __builtin_amdgcn_sched_barrier(0);                                          \
    __builtin_amdgcn_s_setprio(1);                                              \
    _Pragma("unroll") for (int m = 0; m < 4; ++m)                               \
      _Pragma("unroll") for (int nn = 0; nn < 2; ++nn)                          \
        _Pragma("unroll") for (int ks = 0; ks < 2; ++ks)                        \
          acc[(MG) * 4 + m][(NP) * 2 + nn] =                                    \
              __builtin_amdgcn_mfma_f32_16x16x32_bf16(                          \
                  af[m][ks], bf[(NP) * 2 + nn][ks],                             \
                  acc[(MG) * 4 + m][(NP) * 2 + nn], 0, 0, 0);                   \
    __builtin_amdgcn_s_setprio(0);                                              \
    WAIT_STMT;                                                                  \
    __builtin_amdgcn_sched_barrier(0);                                          \
    __builtin_amdgcn_s_barrier();                                               \
    __builtin_amdgcn_sched_barrier(0);                                          \
  }

__global__ __launch_bounds__(512, 2)
void gemm8p(const unsigned short* __restrict__ A, const unsigned short* __restrict__ B,
            const float* __restrict__ bias, const float* __restrict__ resid,
            float* __restrict__ Cf, unsigned short* __restrict__ Cb,
            int M, int N, int K, int relu) {
  extern __shared__ char smem[];   // 131072: 2 bufs x (A 32K + B 32K)

  const int t = threadIdx.x;
  const int lane = t & 63;
  const int wv = t >> 6;
  const int wm = wv >> 2;
  const int wn = wv & 3;
  const int fr = lane & 15;
  const int fq = lane >> 4;

  const int nwg = gridDim.x;
  const int orig = blockIdx.x;
  const int q8 = nwg >> 3;
  const int wgid = (orig & 7) * q8 + (orig >> 3);
  const int stid = wgid >> 2, within = wgid & 3;
  const int sm = within & 1, sn = within >> 1;
  const int Msup = M >> 9;
  const int stm = stid % Msup, stn = stid / Msup;
  const int m0 = (stm * 2 + sm) * 256;
  const int n0 = (stn * 2 + sn) * 256;

  f32x4 acc[8][4];
#pragma unroll
  for (int m = 0; m < 8; ++m)
#pragma unroll
    for (int n = 0; n < 4; ++n) acc[m][n] = (f32x4){0.f, 0.f, 0.f, 0.f};

  const int nk = K / 64;
  const int nj = nk / 2;

  sthalf8(A, m0, K, 0, smem, 0, 0, t);
  sthalf8(A, m0, K, 0, smem, 0, 1, t);
  sthalf8(B, n0, K, 0, smem, 1, 0, t);
  sthalf8(B, n0, K, 0, smem, 1, 1, t);
  sthalf8(B, n0, K, 1, smem, 1, 0, t);
  sthalf8(B, n0, K, 1, smem, 1, 1, t);
  VM4_;
  __builtin_amdgcn_sched_barrier(0);
  __builtin_amdgcn_s_barrier();
  __builtin_amdgcn_sched_barrier(0);

  bf16x8 af[4][2];
  bf16x8 bf[4][2];

  for (int j = 0; j < nj; ++j) {
    const bool st = (j + 1 < nj);
    PHASE8(0, 0, 0, 1, 1, sthalf8(A, m0, K, 2 * j + 1, smem, 0, 0, t), );
    PHASE8(0, 0, 1, 0, 1, sthalf8(A, m0, K, 2 * j + 1, smem, 0, 1, t), );
    PHASE8(0, 1, 1, 1, 0,
           if (st) sthalf8(B, n0, K, 2 * j + 2, smem, 1, 0, t), );
    PHASE8(0, 1, 0, 0, 0,
           if (st) sthalf8(B, n0, K, 2 * j + 2, smem, 1, 1, t),
           { if (st) { VM4_; } else { VM0_; } });
    PHASE8(65536, 0, 0, 1, 1,
           if (st) sthalf8(A, m0, K, 2 * j + 2, smem, 0, 0, t), );
    PHASE8(65536, 0, 1, 0, 1,
           if (st) sthalf8(A, m0, K, 2 * j + 2, smem, 0, 1, t), );
    PHASE8(65536, 1, 1, 1, 0,
           if (st) sthalf8(B, n0, K, 2 * j + 3, smem, 1, 0, t), );
    PHASE8(65536, 1, 0, 0, 0,
           if (st) sthalf8(B, n0, K, 2 * j + 3, smem, 1, 1, t),
           { if (st) { VM4_; } });
  }

  float* slab = (float*)(smem + wv * 4352);
#pragma unroll
  for (int m = 0; m < 8; ++m) {
#pragma unroll
    for (int n = 0; n < 4; ++n)
#pragma unroll
      for (int j = 0; j < 4; ++j)
        slab[(fq * 4 + j) * 68 + n * 16 + fr] = acc[m][n][j];
    int rg0 = m0 + wm * 128 + m * 16;
#pragma unroll
    for (int it = 0; it < 4; ++it) {
      int u = it * 64 + lane;
      int row = u >> 4, seg = u & 15;
      float4 v = *(const float4*)&slab[row * 68 + seg * 4];
      int col = n0 + wn * 64 + seg * 4;
      float4 b4 = *(const float4*)&bias[col];
      v.x += b4.x; v.y += b4.y; v.z += b4.z; v.w += b4.w;
      if (relu) {
        v.x = fmaxf(v.x, 0.f); v.y = fmaxf(v.y, 0.f);
        v.z = fmaxf(v.z, 0.f); v.w = fmaxf(v.w, 0.f);
      }
      size_t idx = (size_t)(rg0 + row) * N + col;
      if (resid) {
        float4 r4 = *(const float4*)&resid[idx];
        v.x += r4.x; v.y += r4.y; v.z += r4.z; v.w += r4.w;
      }
      if (Cf) {
        *(float4*)&Cf[idx] = v;
      } else {
        ushort4 ob;
        ob.x = f2bf(v.x); ob.y = f2bf(v.y); ob.z = f2bf(v.z); ob.w = f2bf(v.w);
        *(ushort4*)&Cb[idx] = ob;
      }
    }
  }
}

// ---------------------------------------------------------------------------
// gemm8p128: the gemm8p fine-phase schedule at BM=256, BN=128 (full-GPU grids
// for N=1024 shapes; used for out-proj and ff2). 8 waves as 4M x 2N, per-wave
// 64x64 (acc[4][4]). LDS 2 bufs x (A 32K + B 16K) = 96 KB.
// 8 phases per K-tile pair, each = (MG m-half) x (NP n-pair) x K=64 -> 8 MFMA.
// Phase reads: P1 afMG0+bfNP0 | P2 bfNP1 | P3 afMG1 | P4 none (x2 tiles).
// Staging (region-safety proven): A(k1)h0@P1, A(k1)h1@P2 -> buf1A (last read
// prev P7); B(k0+2)@P3 -> buf0B (last read P2); A(k0+2)h0@P4, h1@P5 -> buf0A
// (last read P3); B(k1+2)@P7 -> buf1B (last read P6).
// vmcnt ledger (2 loads/quantum; steady pool 2): P1..P4 -> 10 outstanding;
// vmcnt(4)@P4 lands B(k1)+A(k1) [tile k1]; P5,P7 -> 8; vmcnt(2)@P8 lands
// B(k0+2)+A(k0+2) [tile k0+2]. Prologue A(0),B(0),B(1) + vmcnt(2).
// Last pair: no future staging, vmcnt(0)@P4.
// ---------------------------------------------------------------------------
__device__ inline void stA128(const unsigned short* G, int m0, int K, int kt,
                              int half, char* smem_, int t) {
  char* dst = smem_ + ((kt & 1) * 49152) + half * 16384;
#pragma unroll
  for (int i = 0; i < 2; ++i) {
    int g = i * 512 + t;
    int r = g >> 3, sl = g & 7;
    int c = sl ^ (r & 7);
    gload16(G + (size_t)(m0 + half * 128 + r) * K + kt * 64 + c * 8, dst + g * 16);
  }
}
__device__ inline void stB128(const unsigned short* G, int n0, int K, int kt,
                              char* smem_, int t) {
  char* dst = smem_ + ((kt & 1) * 49152) + 32768;
#pragma unroll
  for (int i = 0; i < 2; ++i) {
    int g = i * 512 + t;
    int r = g >> 3, sl = g & 7;
    int c = sl ^ (r & 7);
    gload16(G + (size_t)(n0 + r) * K + kt * 64 + c * 8, dst + g * 16);
  }
}

#define PH128(bufofs, MG, NP, LA, LB, STAGE_STMT, WAIT_STMT)                    \
  {                                                                             \
    if (LA) {                                                                   \
      _Pragma("unroll") for (int mm = 0; mm < 2; ++mm) {                        \
        int arow = wm * 64 + ((MG) * 2 + mm) * 16 + fr;                         \
        _Pragma("unroll") for (int ks = 0; ks < 2; ++ks)                        \
          af[mm][ks] = *(const bf16x8*)(smem + (bufofs) + arow * 128 +          \
                        (((ks * 4 + fq) ^ (arow & 7)) * 16));                   \
      }                                                                         \
    }                                                                           \
    if (LB) {                                                                   \
      _Pragma("unroll") for (int nn = 0; nn < 2; ++nn) {                        \
        int n = (NP) * 2 + nn;                                                  \
        int brow = wn * 64 + n * 16 + fr;                                       \
        _Pragma("unroll") for (int ks = 0; ks < 2; ++ks)                        \
          bf[(NP) * 2 + nn][ks] = *(const bf16x8*)(smem + (bufofs) + 32768 +    \
                        brow * 128 + (((ks * 4 + fq) ^ (brow & 7)) * 16));      \
      }                                                                         \
    }                                                                           \
    STAGE_STMT;                                                                 \
    __builtin_amdgcn_sched_barrier(0);                                          \
    __builtin_amdgcn_s_barrier();                                               \
    asm volatile("s_waitcnt lgkmcnt(0)" ::: "memory");                          \
    __builtin_amdgcn_sched_barrier(0);                                          \
    __builtin_amdgcn_s_setprio(1);                                              \
    _Pragma("unroll") for (int mm = 0; mm < 2; ++mm)                            \
      _Pragma("unroll") for (int nn = 0; nn < 2; ++nn)                          \
        _Pragma("unroll") for (int ks = 0; ks < 2; ++ks)                        \
          acc[(MG) * 2 + mm][(NP) * 2 + nn] =                                   \
              __builtin_amdgcn_mfma_f32_16x16x32_bf16(                          \
                  af[mm][ks], bf[(NP) * 2 + nn][ks],                            \
                  acc[(MG) * 2 + mm][(NP) * 2 + nn], 0, 0, 0);                  \
    __builtin_amdgcn_s_setprio(0);                                              \
    WAIT_STMT;                                                                  \
    __builtin_amdgcn_sched_barrier(0);                                          \
    __builtin_amdgcn_s_barrier();                                               \
    __builtin_amdgcn_sched_barrier(0);                                          \
  }

__global__ __launch_bounds__(512, 2)
void gemm8p128(const unsigned short* __restrict__ A, const unsigned short* __restrict__ B,
               const float* __restrict__ bias, const float* __restrict__ resid,
               float* __restrict__ Cf, unsigned short* __restrict__ Cb,
               int M, int N, int K, int relu) {
  extern __shared__ char smem[];   // 98304: 2 bufs x (A 32K + B 16K)

  const int t = threadIdx.x;
  const int lane = t & 63;
  const int wv = t >> 6;
  const int wm = wv >> 1;         // 0..3: rows wm*64..+64
  const int wn = wv & 1;          // 0..1: cols wn*64..+64
  const int fr = lane & 15;
  const int fq = lane >> 4;

  // XCD remap + 2x2 supertile (nwg = 256)
  const int nwg = gridDim.x;
  const int orig = blockIdx.x;
  const int q8 = nwg >> 3;
  const int wgid = (orig & 7) * q8 + (orig >> 3);
  const int stid = wgid >> 2, within = wgid & 3;
  const int sm = within & 1, sn = within >> 1;
  const int Msup = M >> 9;                   // (M/256)/2 = 16
  const int stm = stid % Msup, stn = stid / Msup;
  const int m0 = (stm * 2 + sm) * 256;
  const int n0 = (stn * 2 + sn) * 128;

  f32x4 acc[4][4];
#pragma unroll
  for (int m = 0; m < 4; ++m)
#pragma unroll
    for (int n = 0; n < 4; ++n) acc[m][n] = (f32x4){0.f, 0.f, 0.f, 0.f};

  const int nk = K / 64;   // 16 or 64 (even)
  const int nj = nk / 2;

  // prologue: A(0) h0,h1 (4 loads), B(0) (2), B(1) (2); vmcnt(2) -> A0+B0 in
  stA128(A, m0, K, 0, 0, smem, t);
  stA128(A, m0, K, 0, 1, smem, t);
  stB128(B, n0, K, 0, smem, t);
  stB128(B, n0, K, 1, smem, t);
  VM2_;
  __builtin_amdgcn_sched_barrier(0);
  __builtin_amdgcn_s_barrier();
  __builtin_amdgcn_sched_barrier(0);

  bf16x8 af[2][2];
  bf16x8 bf[4][2];

  for (int j = 0; j < nj; ++j) {
    const bool st = (j + 1 < nj);
    const int k1 = 2 * j + 1;
    // ---- tile k0 (buf0) ----
    PH128(0, 0, 0, 1, 1, stA128(A, m0, K, k1, 0, smem, t), );
    PH128(0, 0, 1, 0, 1, stA128(A, m0, K, k1, 1, smem, t), );
    PH128(0, 1, 0, 1, 0,
          if (st) stB128(B, n0, K, k1 + 1, smem, t), );
    PH128(0, 1, 1, 0, 0,
          if (st) stA128(A, m0, K, k1 + 1, 0, smem, t),
          { if (st) { VM4_; } else { VM0_; } });
    // ---- tile k1 (buf1) ----
    PH128(49152, 0, 0, 1, 1,
          if (st) stA128(A, m0, K, k1 + 1, 1, smem, t), );
    PH128(49152, 0, 1, 0, 1, , );
    PH128(49152, 1, 0, 1, 0,
          if (st) stB128(B, n0, K, k1 + 2, smem, t), );
    PH128(49152, 1, 1, 0, 0, ,
          { if (st) { VM2_; } });
  }

  // epilogue: per-wave slab (16x68 f32), coalesced stores (all buffers dead).
  float* slab = (float*)(smem + wv * 4352);
#pragma unroll
  for (int m = 0; m < 4; ++m) {
#pragma unroll
    for (int n = 0; n < 4; ++n)
#pragma unroll
      for (int j = 0; j < 4; ++j)
        slab[(fq * 4 + j) * 68 + n * 16 + fr] = acc[m][n][j];
    int rg0 = m0 + wm * 64 + m * 16;
#pragma unroll
    for (int it = 0; it < 4; ++it) {
      int u = it * 64 + lane;
      int row = u >> 4, seg = u & 15;
      float4 v = *(const float4*)&slab[row * 68 + seg * 4];
      int col = n0 + wn * 64 + seg * 4;
      float4 b4 = *(const float4*)&bias[col];
      v.x += b4.x; v.y += b4.y; v.z += b4.z; v.w += b4.w;
      if (relu) {
        v.x = fmaxf(v.x, 0.f); v.y = fmaxf(v.y, 0.f);
        v.z = fmaxf(v.z, 0.f); v.w = fmaxf(v.w, 0.f);
      }
      size_t idx = (size_t)(rg0 + row) * N + col;
      if (resid) {
        float4 r4 = *(const float4*)&resid[idx];
        v.x += r4.x; v.y += r4.y; v.z += r4.z; v.w += r4.w;
      }
      if (Cf) {
        *(float4*)&Cf[idx] = v;
      } else {
        ushort4 ob;
        ob.x = f2bf(v.x); ob.y = f2bf(v.y); ob.z = f2bf(v.z); ob.w = f2bf(v.w);
        *(ushort4*)&Cb[idx] = ob;
      }
    }
  }
}

// ---------------------------------------------------------------------------
// V transpose: qkvb V-part -> vtb [(bh*64 + d)][s].
// ---------------------------------------------------------------------------
__global__ __launch_bounds__(256)
void vtrans_kernel(const unsigned short* __restrict__ qkvb, unsigned short* __restrict__ vtb) {
  __shared__ __align__(16) unsigned short tile[64][64];
  const int st = blockIdx.x;
  const int bh = blockIdx.y;
  const int b = bh >> 4, h = bh & 15;
  const int t = threadIdx.x;
#pragma unroll
  for (int p = 0; p < 2; ++p) {
    int item = p * 256 + t;
    int r = item >> 3, c8 = item & 7;
    const unsigned short* src =
        qkvb + (size_t)(b * SEQ + st * 64 + r) * (3 * DMODEL) + 2048 + h * 64 + c8 * 8;
    *(uint4*)&tile[r][(c8 ^ (r & 7)) * 8] = *(const uint4*)src;
  }
  __syncthreads();
#pragma unroll
  for (int p = 0; p < 2; ++p) {
    int item = p * 256 + t;
    int d = item & 63, s8 = item >> 6;
    unsigned short v[8];
#pragma unroll
    for (int e = 0; e < 8; ++e) {
      int s = s8 * 8 + e;
      v[e] = tile[s][(((d >> 3) ^ (s & 7)) * 8) + (d & 7)];
    }
    uint4 u;
    u.x = (unsigned int)v[0] | ((unsigned int)v[1] << 16);
    u.y = (unsigned int)v[2] | ((unsigned int)v[3] << 16);
    u.z = (unsigned int)v[4] | ((unsigned int)v[5] << 16);
    u.w = (unsigned int)v[6] | ((unsigned int)v[7] << 16);
    *(uint4*)(vtb + ((size_t)bh * 64 + d) * SEQ + st * 64 + s8 * 8) = u;
  }
}

// ---------------------------------------------------------------------------
// MFMA flash attention v5 (round-9 structure, reverted to — best measured).
// ---------------------------------------------------------------------------
__global__ __launch_bounds__(512, 4)
void attn_kernel(const unsigned short* __restrict__ qkv, const unsigned short* __restrict__ vtb,
                 unsigned short* __restrict__ ctxb) {
  __shared__ __align__(16) unsigned short Ks[2][64][64];
  __shared__ __align__(16) unsigned short Vts[2][64][64];
  __shared__ __align__(16) unsigned short Slab[8][32][64];

  const int t = threadIdx.x;
  const int lane = t & 63;
  const int wq = t >> 6;
  const int l31 = lane & 31;
  const int hi1 = lane >> 5;
  const int bid = blockIdx.x;
  const int bh = bid & 63;
  const int qt = bid >> 6;
  const int b = bh >> 4, h = bh & 15;
  const int q0 = qt * 256;

  const size_t RS = 3 * DMODEL;
  const unsigned short* qb = qkv + (size_t)b * SEQ * RS + h * DHEAD;
  const unsigned short* kb = qb + DMODEL;

  bf16x8 qf[4];
  {
    const unsigned short* qrow = qb + (size_t)(q0 + wq * 32 + l31) * RS;
#pragma unroll
    for (int s = 0; s < 4; ++s)
      qf[s] = *(const bf16x8*)(qrow + s * 16 + hi1 * 8);
  }

  const unsigned short* kgl =
      kb + (size_t)(wq * 8 + (lane >> 3)) * RS + ((lane & 7) ^ (lane >> 3)) * 8;
  const unsigned short* vgl =
      vtb + ((size_t)bh * 64 + wq * 8 + (lane >> 3)) * SEQ + ((lane & 7) ^ (lane >> 3)) * 8;

  f32x16 oacc[2] = {};
  float lacc = 0.f;

  gload16(kgl, (char*)&Ks[0][wq * 8][0]);
  gload16(vgl, (char*)&Vts[0][wq * 8][0]);
  __syncthreads();

  const float C = 0.18033688011112042f;   // 0.125 * log2(e)

  for (int kt = 0; kt < NT; ++kt) {
    const int cur = kt & 1;
    if (kt + 1 < NT) {
      gload16(kgl + (size_t)(kt + 1) * 64 * RS, (char*)&Ks[cur ^ 1][wq * 8][0]);
      gload16(vgl + (size_t)(kt + 1) * 64, (char*)&Vts[cur ^ 1][wq * 8][0]);
    }

    f32x16 sacc[2] = {};
    __builtin_amdgcn_s_setprio(1);
#pragma unroll
    for (int s = 0; s < 4; ++s) {
#pragma unroll
      for (int kvt = 0; kvt < 2; ++kvt) {
        int row = kvt * 32 + l31;
        bf16x8 kf = *(const bf16x8*)&Ks[cur][row][(((2 * s + hi1) ^ (row & 7)) * 8)];
        sacc[kvt] = __builtin_amdgcn_mfma_f32_32x32x16_bf16(kf, qf[s], sacc[kvt], 0, 0, 0);
      }
    }
    __builtin_amdgcn_s_setprio(0);

#pragma unroll
    for (int kvt = 0; kvt < 2; ++kvt) {
      float p[16];
#pragma unroll
      for (int r = 0; r < 16; ++r) p[r] = fexp2(sacc[kvt][r] * C);
      float ps = 0.f;
#pragma unroll
      for (int r = 0; r < 16; ++r) ps += p[r];
      lacc += ps;
#pragma unroll
      for (int half = 0; half < 2; ++half) {
        const int lo = half * 8;
        unsigned int x0 = cvtpk(p[lo + 0], p[lo + 1]);
        unsigned int x1 = cvtpk(p[lo + 2], p[lo + 3]);
        unsigned int y0 = cvtpk(p[lo + 4], p[lo + 5]);
        unsigned int y1 = cvtpk(p[lo + 6], p[lo + 7]);
        plswap(x0, y0);
        plswap(x1, y1);
        bf16x8 pa = __builtin_bit_cast(bf16x8, (u32x4){x0, x1, y0, y1});
        const int s2 = kvt * 2 + half;
        __builtin_amdgcn_s_setprio(1);
#pragma unroll
        for (int dt = 0; dt < 2; ++dt) {
          int vrow = dt * 32 + l31;
          bf16x8 vf = *(const bf16x8*)&Vts[cur][vrow][(((2 * s2 + hi1) ^ (vrow & 7)) * 8)];
          oacc[dt] = __builtin_amdgcn_mfma_f32_32x32x16_bf16(pa, vf, oacc[dt], 0, 0, 0);
        }
        __builtin_amdgcn_s_setprio(0);
      }
    }
    __syncthreads();
  }

  lacc += __shfl_xor(lacc, 32);
  float inv = 1.0f / lacc;

  float iv[16];
#pragma unroll
  for (int r = 0; r < 16; ++r)
    iv[r] = __shfl(inv, (r & 3) + 8 * (r >> 2) + 4 * hi1);

#pragma unroll
  for (int dt = 0; dt < 2; ++dt) {
    const int chunk = dt * 4 + (l31 >> 3);
    const int e7 = l31 & 7;
#pragma unroll
    for (int r = 0; r < 16; ++r) {
      int qp = (r & 3) + 8 * (r >> 2) + 4 * hi1;
      Slab[wq][qp][((chunk ^ (qp & 7)) * 8) + e7] = f2bf(oacc[dt][r] * iv[r]);
    }
  }
#pragma unroll
  for (int it = 0; it < 4; ++it) {
    int u = it * 64 + lane;
    int row = u >> 3, s = u & 7;
    uint4 v = *(const uint4*)&Slab[wq][row][((s ^ (row & 7)) * 8)];
    *(uint4*)(ctxb + (size_t)(b * SEQ + q0 + wq * 32 + row) * DMODEL + h * DHEAD + s * 8) = v;
  }
}

// ---------------------------------------------------------------------------
// LayerNorm with optional secondary bf16 output.
// ---------------------------------------------------------------------------
__global__ __launch_bounds__(256)
void ln_kernel(const float* __restrict__ Z, const float* __restrict__ g,
               const float* __restrict__ bta, float* __restrict__ Y,
               unsigned short* __restrict__ Yb) {
  const int row = blockIdx.x;
  const float4* z4 = (const float4*)(Z + (size_t)row * DMODEL);
  float4 v = z4[threadIdx.x];
  float s = v.x + v.y + v.z + v.w;
  float ss = fmaf(v.x, v.x, fmaf(v.y, v.y, fmaf(v.z, v.z, v.w * v.w)));
#pragma unroll
  for (int o = 32; o >= 1; o >>= 1) {
    s += __shfl_xor(s, o);
    ss += __shfl_xor(ss, o);
  }
  __shared__ float red[8];
  int w = threadIdx.x >> 6;
  if ((threadIdx.x & 63) == 0) { red[w] = s; red[4 + w] = ss; }
  __syncthreads();
  s = red[0] + red[1] + red[2] + red[3];
  ss = red[4] + red[5] + red[6] + red[7];
  float mu = s * (1.0f / DMODEL);
  float var = ss * (1.0f / DMODEL) - mu * mu;
  float rs = rsqrtf(var + LNEPS);
  float4 gg = ((const float4*)g)[threadIdx.x];
  float4 bb = ((const float4*)bta)[threadIdx.x];
  float4 o;
  o.x = (v.x - mu) * rs * gg.x + bb.x;
  o.y = (v.y - mu) * rs * gg.y + bb.y;
  o.z = (v.z - mu) * rs * gg.z + bb.z;
  o.w = (v.w - mu) * rs * gg.w + bb.w;
  ((float4*)(Y + (size_t)row * DMODEL))[threadIdx.x] = o;
  if (Yb) {
    ushort4 ob;
    ob.x = f2bf(o.x); ob.y = f2bf(o.y); ob.z = f2bf(o.z); ob.w = f2bf(o.w);
    ((ushort4*)(Yb + (size_t)row * DMODEL))[threadIdx.x] = ob;
  }
}

// ---------------------------------------------------------------------------
extern "C" void kernel_launch(void* const* d_in, const int* in_sizes, int n_in,
                              void* d_out, int out_size, void* d_ws, size_t ws_size,
                              hipStream_t stream) {
  const int* tokens       = (const int*)d_in[0];
  const float* emb        = (const float*)d_in[1];
  const float* in_proj_w  = (const float*)d_in[2];
  const float* in_proj_b  = (const float*)d_in[3];
  const float* out_proj_w = (const float*)d_in[4];
  const float* out_proj_b = (const float*)d_in[5];
  const float* w1         = (const float*)d_in[6];
  const float* b1         = (const float*)d_in[7];
  const float* w2         = (const float*)d_in[8];
  const float* b2         = (const float*)d_in[9];
  const float* g1         = (const float*)d_in[10];
  const float* beta1      = (const float*)d_in[11];
  const float* g2         = (const float*)d_in[12];
  const float* beta2      = (const float*)d_in[13];
  float* out = (float*)d_out;

  char* ws = (char*)d_ws;
  const size_t MB = 1ull << 20;
  unsigned short* inwb  = (unsigned short*)(ws + 0 * MB);
  unsigned short* outwb = (unsigned short*)(ws + 6 * MB);
  unsigned short* w1b   = (unsigned short*)(ws + 8 * MB);
  unsigned short* w2b   = (unsigned short*)(ws + 16 * MB);
  float* x              = (float*)(ws + 24 * MB);
  unsigned short* xb    = (unsigned short*)(ws + 56 * MB);
  unsigned short* qkvb  = (unsigned short*)(ws + 72 * MB);
  unsigned short* vtb   = (unsigned short*)(ws + 120 * MB);
  unsigned short* ctxb  = (unsigned short*)(ws + 56 * MB);
  float* h              = (float*)(ws + 72 * MB);
  unsigned short* hb    = (unsigned short*)(ws + 104 * MB);
  unsigned short* ffbb  = (unsigned short*)(ws + 120 * MB);
  float* y2             = (float*)(ws + 24 * MB);

  const size_t GLDSP  = 131072;   // gemm8p: 128 KB
  const size_t GLDSPN = 98304;    // gemm8p128: 96 KB

  embed_kernel<<<(MROWS * (DMODEL / 2) + 255) / 256, 256, 0, stream>>>(tokens, emb, x, xb);
  cvt4_kernel<<<12288, 256, 0, stream>>>(in_proj_w, out_proj_w, w1, w2,
                                         inwb, outwb, w1b, w2b);
  // qkv = x @ in_proj_w^T + b  (bf16 out)   [384 blocks, 8-phase 256x256]
  gemm8p<<<(MROWS / 256) * (3 * DMODEL / 256), 512, GLDSP, stream>>>(
      xb, inwb, in_proj_b, nullptr, nullptr, qkvb, MROWS, 3 * DMODEL, DMODEL, 0);
  // V^T pre-transpose
  vtrans_kernel<<<dim3(SEQ / 64, BATCH * NH), 256, 0, stream>>>(qkvb, vtb);
  // flash attention v5 -> ctxb (bf16)   [512 blocks]
  attn_kernel<<<(SEQ / 256) * (BATCH * NH), 512, 0, stream>>>(qkvb, vtb, ctxb);
  // h = ctx @ out_proj_w^T + b + x  (f32 out)   [256 blocks, 8-phase 256x128]
  gemm8p128<<<(MROWS / 256) * (DMODEL / 128), 512, GLDSPN, stream>>>(
      ctxb, outwb, out_proj_b, x, h, nullptr, MROWS, DMODEL, DMODEL, 0);
  ln_kernel<<<MROWS, 256, 0, stream>>>(h, g1, beta1, h, hb);
  // ffb = relu(h @ w1^T + b1)  (bf16 out)   [512 blocks, 8-phase 256x256]
  gemm8p<<<(MROWS / 256) * (DFF / 256), 512, GLDSP, stream>>>(
      hb, w1b, b1, nullptr, nullptr, ffbb, MROWS, DFF, DMODEL, 1);
  // y2 = ffb @ w2^T + b2 + h  (f32 out)   [256 blocks, 8-phase 256x128]
  gemm8p128<<<(MROWS / 256) * (DMODEL / 128), 512, GLDSPN, stream>>>(
      ffbb, w2b, b2, h, y2, nullptr, MROWS, DMODEL, DFF, 0);
  ln_kernel<<<MROWS, 256, 0, stream>>>(y2, g2, beta2, out, nullptr);
}

// Round 13
// 391.679 us; speedup vs baseline: 1.0410x; 1.0241x over previous
//
#include <hip/hip_runtime.h>
#include <math.h>

#define DMODEL 1024
#define NH 16
#define DHEAD 64
#define DFF 4096
#define BATCH 4
#define SEQ 2048
#define MROWS (BATCH * SEQ)   // 8192
#define LNEPS 1e-5f
#define NT (SEQ / 64)         // 32 kv tiles

typedef __attribute__((ext_vector_type(8))) short bf16x8;
typedef __attribute__((ext_vector_type(4))) float f32x4;
typedef __attribute__((ext_vector_type(16))) float f32x16;
typedef __attribute__((ext_vector_type(4))) unsigned int u32x4;

__device__ inline unsigned short f2bf(float f) {
  unsigned int u = __float_as_uint(f);
  unsigned int r = (u + 0x7fffu + ((u >> 16) & 1u)) >> 16;  // RNE
  return (unsigned short)r;
}
__device__ inline float bf2f(unsigned short b) {
  return __uint_as_float(((unsigned int)b) << 16);
}

__device__ inline void gload16(const unsigned short* g, char* l) {
  __builtin_amdgcn_global_load_lds(
      (const __attribute__((address_space(1))) unsigned int*)g,
      (__attribute__((address_space(3))) unsigned int*)l, 16, 0, 0);
}

__device__ inline float fexp2(float x) {
  float r;
  asm("v_exp_f32 %0, %1" : "=v"(r) : "v"(x));
  return r;
}
__device__ inline unsigned int cvtpk(float lo, float hi) {
  unsigned int r;
  asm("v_cvt_pk_bf16_f32 %0, %1, %2" : "=v"(r) : "v"(lo), "v"(hi));
  return r;
}
__device__ inline void plswap(unsigned int& a, unsigned int& b) {
  asm("v_permlane32_swap_b32 %0, %1" : "+v"(a), "+v"(b));
}

// ---------------------------------------------------------------------------
// Embedding + positional encoding -> bf16 only (residual stream is bf16 now).
// ---------------------------------------------------------------------------
__global__ __launch_bounds__(256)
void embed_kernel(const int* __restrict__ tokens, const float* __restrict__ emb,
                  unsigned short* __restrict__ Xb) {
  const int HALF = DMODEL / 2;
  int idx = blockIdx.x * 256 + threadIdx.x;
  if (idx >= MROWS * HALF) return;
  int row = idx / HALF;
  int j = idx - row * HALF;
  int s = row & (SEQ - 1);
  int tok = tokens[row];
  float2 e = ((const float2*)(emb + (size_t)tok * DMODEL))[j];
  float denom = powf(10000.0f, (2.0f * (float)(2 * j)) / (float)DMODEL);
  float ang = (float)s / denom;
  float sn, cs;
  sincosf(ang, &sn, &cs);
  ushort2 ob;
  ob.x = f2bf(e.x + sn);
  ob.y = f2bf(e.y + cs);
  ((ushort2*)(Xb + (size_t)row * DMODEL))[j] = ob;
}

// ---------------------------------------------------------------------------
// Fused fp32 -> bf16 conversion of all four weight matrices (one launch).
// ---------------------------------------------------------------------------
__global__ __launch_bounds__(256)
void cvt4_kernel(const float* __restrict__ a, const float* __restrict__ b,
                 const float* __restrict__ c, const float* __restrict__ d,
                 unsigned short* __restrict__ oa, unsigned short* __restrict__ ob,
                 unsigned short* __restrict__ oc, unsigned short* __restrict__ od) {
  int i = blockIdx.x * 256 + threadIdx.x;
  const float* src; unsigned short* dst; int off;
  if (i < 786432)       { src = a; dst = oa; off = 0; }
  else if (i < 1048576) { src = b; dst = ob; off = 786432; }
  else if (i < 2097152) { src = c; dst = oc; off = 1048576; }
  else                  { src = d; dst = od; off = 2097152; }
  int j = i - off;
  float4 v = ((const float4*)src)[j];
  ushort4 o;
  o.x = f2bf(v.x); o.y = f2bf(v.y); o.z = f2bf(v.z); o.w = f2bf(v.w);
  ((ushort4*)dst)[j] = o;
}

// ---------------------------------------------------------------------------
// gemm8p: 8-phase 256x256 GEMM (round-10 structure; qkv and ff1).
// ---------------------------------------------------------------------------
__device__ inline void sthalf8(const unsigned short* G, int grow0, int K, int kt,
                               char* smem_, int isB, int half, int t) {
  char* dst = smem_ + ((kt & 1) * 65536) + isB * 32768 + half * 16384;
#pragma unroll
  for (int i = 0; i < 2; ++i) {
    int g = i * 512 + t;
    int r = g >> 3, sl = g & 7;
    int c = sl ^ (r & 7);
    gload16(G + (size_t)(grow0 + half * 128 + r) * K + kt * 64 + c * 8, dst + g * 16);
  }
}

#define VM4_ asm volatile("s_waitcnt vmcnt(4)" ::: "memory")
#define VM2_ asm volatile("s_waitcnt vmcnt(2)" ::: "memory")
#define VM0_ asm volatile("s_waitcnt vmcnt(0)" ::: "memory")

#define PHASE8(bufofs, MG, NP, LA, LB, STAGE_STMT, WAIT_STMT)                   \
  {                                                                             \
    if (LA) {                                                                   \
      _Pragma("unroll") for (int m = 0; m < 4; ++m) {                           \
        int arow = wm * 128 + (MG) * 64 + m * 16 + fr;                          \
        _Pragma("unroll") for (int ks = 0; ks < 2; ++ks)                        \
          af[m][ks] = *(const bf16x8*)(smem + (bufofs) + arow * 128 +           \
                        (((ks * 4 + fq) ^ (arow & 7)) * 16));                   \
      }                                                                         \
    }                                                                           \
    if (LB) {                                                                   \
      _Pragma("unroll") for (int nn = 0; nn < 2; ++nn) {                        \
        int n = (NP) * 2 + nn;                                                  \
        int brow = wn * 64 + n * 16 + fr;                                       \
        _Pragma("unroll") for (int ks = 0; ks < 2; ++ks)                        \
          bf[(NP) * 2 + nn][ks] = *(const bf16x8*)(smem + (bufofs) + 32768 +    \
                        brow * 128 + (((ks * 4 + fq) ^ (brow & 7)) * 16));      \
      }                                                                         \
    }                                                                           \
    STAGE_STMT;                                                                 \
    __builtin_amdgcn_sched_barrier(0);                                          \
    __builtin_amdgcn_s_barrier();                                               \
    asm volatile("s_waitcnt lgkmcnt(0)" ::: "memory");                          \
    __builtin_amdgcn_sched_barrier(0);                                          \
    __builtin_amdgcn_s_setprio(1);                                              \
    _Pragma("unroll") for (int m = 0; m < 4; ++m)                               \
      _Pragma("unroll") for (int nn = 0; nn < 2; ++nn)                          \
        _Pragma("unroll") for (int ks = 0; ks < 2; ++ks)                        \
          acc[(MG) * 4 + m][(NP) * 2 + nn] =                                    \
              __builtin_amdgcn_mfma_f32_16x16x32_bf16(                          \
                  af[m][ks], bf[(NP) * 2 + nn][ks],                             \
                  acc[(MG) * 4 + m][(NP) * 2 + nn], 0, 0, 0);                   \
    __builtin_amdgcn_s_setprio(0);                                              \
    WAIT_STMT;                                                                  \
    __builtin_amdgcn_sched_barrier(0);                                          \
    __builtin_amdgcn_s_barrier();                                               \
    __builtin_amdgcn_sched_barrier(0);                                          \
  }

__global__ __launch_bounds__(512, 2)
void gemm8p(const unsigned short* __restrict__ A, const unsigned short* __restrict__ B,
            const float* __restrict__ bias, const float* __restrict__ resid,
            float* __restrict__ Cf, unsigned short* __restrict__ Cb,
            int M, int N, int K, int relu) {
  extern __shared__ char smem[];   // 131072: 2 bufs x (A 32K + B 32K)

  const int t = threadIdx.x;
  const int lane = t & 63;
  const int wv = t >> 6;
  const int wm = wv >> 2;
  const int wn = wv & 3;
  const int fr = lane & 15;
  const int fq = lane >> 4;

  const int nwg = gridDim.x;
  const int orig = blockIdx.x;
  const int q8 = nwg >> 3;
  const int wgid = (orig & 7) * q8 + (orig >> 3);
  const int stid = wgid >> 2, within = wgid & 3;
  const int sm = within & 1, sn = within >> 1;
  const int Msup = M >> 9;
  const int stm = stid % Msup, stn = stid / Msup;
  const int m0 = (stm * 2 + sm) * 256;
  const int n0 = (stn * 2 + sn) * 256;

  f32x4 acc[8][4];
#pragma unroll
  for (int m = 0; m < 8; ++m)
#pragma unroll
    for (int n = 0; n < 4; ++n) acc[m][n] = (f32x4){0.f, 0.f, 0.f, 0.f};

  const int nk = K / 64;
  const int nj = nk / 2;

  sthalf8(A, m0, K, 0, smem, 0, 0, t);
  sthalf8(A, m0, K, 0, smem, 0, 1, t);
  sthalf8(B, n0, K, 0, smem, 1, 0, t);
  sthalf8(B, n0, K, 0, smem, 1, 1, t);
  sthalf8(B, n0, K, 1, smem, 1, 0, t);
  sthalf8(B, n0, K, 1, smem, 1, 1, t);
  VM4_;
  __builtin_amdgcn_sched_barrier(0);
  __builtin_amdgcn_s_barrier();
  __builtin_amdgcn_sched_barrier(0);

  bf16x8 af[4][2];
  bf16x8 bf[4][2];

  for (int j = 0; j < nj; ++j) {
    const bool st = (j + 1 < nj);
    PHASE8(0, 0, 0, 1, 1, sthalf8(A, m0, K, 2 * j + 1, smem, 0, 0, t), );
    PHASE8(0, 0, 1, 0, 1, sthalf8(A, m0, K, 2 * j + 1, smem, 0, 1, t), );
    PHASE8(0, 1, 1, 1, 0,
           if (st) sthalf8(B, n0, K, 2 * j + 2, smem, 1, 0, t), );
    PHASE8(0, 1, 0, 0, 0,
           if (st) sthalf8(B, n0, K, 2 * j + 2, smem, 1, 1, t),
           { if (st) { VM4_; } else { VM0_; } });
    PHASE8(65536, 0, 0, 1, 1,
           if (st) sthalf8(A, m0, K, 2 * j + 2, smem, 0, 0, t), );
    PHASE8(65536, 0, 1, 0, 1,
           if (st) sthalf8(A, m0, K, 2 * j + 2, smem, 0, 1, t), );
    PHASE8(65536, 1, 1, 1, 0,
           if (st) sthalf8(B, n0, K, 2 * j + 3, smem, 1, 0, t), );
    PHASE8(65536, 1, 0, 0, 0,
           if (st) sthalf8(B, n0, K, 2 * j + 3, smem, 1, 1, t),
           { if (st) { VM4_; } });
  }

  float* slab = (float*)(smem + wv * 4352);
#pragma unroll
  for (int m = 0; m < 8; ++m) {
#pragma unroll
    for (int n = 0; n < 4; ++n)
#pragma unroll
      for (int j = 0; j < 4; ++j)
        slab[(fq * 4 + j) * 68 + n * 16 + fr] = acc[m][n][j];
    int rg0 = m0 + wm * 128 + m * 16;
#pragma unroll
    for (int it = 0; it < 4; ++it) {
      int u = it * 64 + lane;
      int row = u >> 4, seg = u & 15;
      float4 v = *(const float4*)&slab[row * 68 + seg * 4];
      int col = n0 + wn * 64 + seg * 4;
      float4 b4 = *(const float4*)&bias[col];
      v.x += b4.x; v.y += b4.y; v.z += b4.z; v.w += b4.w;
      if (relu) {
        v.x = fmaxf(v.x, 0.f); v.y = fmaxf(v.y, 0.f);
        v.z = fmaxf(v.z, 0.f); v.w = fmaxf(v.w, 0.f);
      }
      size_t idx = (size_t)(rg0 + row) * N + col;
      if (resid) {
        float4 r4 = *(const float4*)&resid[idx];
        v.x += r4.x; v.y += r4.y; v.z += r4.z; v.w += r4.w;
      }
      if (Cf) {
        *(float4*)&Cf[idx] = v;
      } else {
        ushort4 ob;
        ob.x = f2bf(v.x); ob.y = f2bf(v.y); ob.z = f2bf(v.z); ob.w = f2bf(v.w);
        *(ushort4*)&Cb[idx] = ob;
      }
    }
  }
}

// ---------------------------------------------------------------------------
// gemm8p128: fine-phase schedule at BM=256, BN=128 (out-proj and ff2).
// Residual may be f32 (resid) or bf16 (residb); output f32 (Cf) or bf16 (Cb).
// ---------------------------------------------------------------------------
__device__ inline void stA128(const unsigned short* G, int m0, int K, int kt,
                              int half, char* smem_, int t) {
  char* dst = smem_ + ((kt & 1) * 49152) + half * 16384;
#pragma unroll
  for (int i = 0; i < 2; ++i) {
    int g = i * 512 + t;
    int r = g >> 3, sl = g & 7;
    int c = sl ^ (r & 7);
    gload16(G + (size_t)(m0 + half * 128 + r) * K + kt * 64 + c * 8, dst + g * 16);
  }
}
__device__ inline void stB128(const unsigned short* G, int n0, int K, int kt,
                              char* smem_, int t) {
  char* dst = smem_ + ((kt & 1) * 49152) + 32768;
#pragma unroll
  for (int i = 0; i < 2; ++i) {
    int g = i * 512 + t;
    int r = g >> 3, sl = g & 7;
    int c = sl ^ (r & 7);
    gload16(G + (size_t)(n0 + r) * K + kt * 64 + c * 8, dst + g * 16);
  }
}

#define PH128(bufofs, MG, NP, LA, LB, STAGE_STMT, WAIT_STMT)                    \
  {                                                                             \
    if (LA) {                                                                   \
      _Pragma("unroll") for (int mm = 0; mm < 2; ++mm) {                        \
        int arow = wm * 64 + ((MG) * 2 + mm) * 16 + fr;                         \
        _Pragma("unroll") for (int ks = 0; ks < 2; ++ks)                        \
          af[mm][ks] = *(const bf16x8*)(smem + (bufofs) + arow * 128 +          \
                        (((ks * 4 + fq) ^ (arow & 7)) * 16));                   \
      }                                                                         \
    }                                                                           \
    if (LB) {                                                                   \
      _Pragma("unroll") for (int nn = 0; nn < 2; ++nn) {                        \
        int n = (NP) * 2 + nn;                                                  \
        int brow = wn * 64 + n * 16 + fr;                                       \
        _Pragma("unroll") for (int ks = 0; ks < 2; ++ks)                        \
          bf[(NP) * 2 + nn][ks] = *(const bf16x8*)(smem + (bufofs) + 32768 +    \
                        brow * 128 + (((ks * 4 + fq) ^ (brow & 7)) * 16));      \
      }                                                                         \
    }                                                                           \
    STAGE_STMT;                                                                 \
    __builtin_amdgcn_sched_barrier(0);                                          \
    __builtin_amdgcn_s_barrier();                                               \
    asm volatile("s_waitcnt lgkmcnt(0)" ::: "memory");                          \
    __builtin_amdgcn_sched_barrier(0);                                          \
    __builtin_amdgcn_s_setprio(1);                                              \
    _Pragma("unroll") for (int mm = 0; mm < 2; ++mm)                            \
      _Pragma("unroll") for (int nn = 0; nn < 2; ++nn)                          \
        _Pragma("unroll") for (int ks = 0; ks < 2; ++ks)                        \
          acc[(MG) * 2 + mm][(NP) * 2 + nn] =                                   \
              __builtin_amdgcn_mfma_f32_16x16x32_bf16(                          \
                  af[mm][ks], bf[(NP) * 2 + nn][ks],                            \
                  acc[(MG) * 2 + mm][(NP) * 2 + nn], 0, 0, 0);                  \
    __builtin_amdgcn_s_setprio(0);                                              \
    WAIT_STMT;                                                                  \
    __builtin_amdgcn_sched_barrier(0);                                          \
    __builtin_amdgcn_s_barrier();                                               \
    __builtin_amdgcn_sched_barrier(0);                                          \
  }

__global__ __launch_bounds__(512, 2)
void gemm8p128(const unsigned short* __restrict__ A, const unsigned short* __restrict__ B,
               const float* __restrict__ bias, const float* __restrict__ resid,
               const unsigned short* __restrict__ residb,
               float* __restrict__ Cf, unsigned short* __restrict__ Cb,
               int M, int N, int K, int relu) {
  extern __shared__ char smem[];   // 98304: 2 bufs x (A 32K + B 16K)

  const int t = threadIdx.x;
  const int lane = t & 63;
  const int wv = t >> 6;
  const int wm = wv >> 1;
  const int wn = wv & 1;
  const int fr = lane & 15;
  const int fq = lane >> 4;

  const int nwg = gridDim.x;
  const int orig = blockIdx.x;
  const int q8 = nwg >> 3;
  const int wgid = (orig & 7) * q8 + (orig >> 3);
  const int stid = wgid >> 2, within = wgid & 3;
  const int sm = within & 1, sn = within >> 1;
  const int Msup = M >> 9;
  const int stm = stid % Msup, stn = stid / Msup;
  const int m0 = (stm * 2 + sm) * 256;
  const int n0 = (stn * 2 + sn) * 128;

  f32x4 acc[4][4];
#pragma unroll
  for (int m = 0; m < 4; ++m)
#pragma unroll
    for (int n = 0; n < 4; ++n) acc[m][n] = (f32x4){0.f, 0.f, 0.f, 0.f};

  const int nk = K / 64;
  const int nj = nk / 2;

  stA128(A, m0, K, 0, 0, smem, t);
  stA128(A, m0, K, 0, 1, smem, t);
  stB128(B, n0, K, 0, smem, t);
  stB128(B, n0, K, 1, smem, t);
  VM2_;
  __builtin_amdgcn_sched_barrier(0);
  __builtin_amdgcn_s_barrier();
  __builtin_amdgcn_sched_barrier(0);

  bf16x8 af[2][2];
  bf16x8 bf[4][2];

  for (int j = 0; j < nj; ++j) {
    const bool st = (j + 1 < nj);
    const int k1 = 2 * j + 1;
    PH128(0, 0, 0, 1, 1, stA128(A, m0, K, k1, 0, smem, t), );
    PH128(0, 0, 1, 0, 1, stA128(A, m0, K, k1, 1, smem, t), );
    PH128(0, 1, 0, 1, 0,
          if (st) stB128(B, n0, K, k1 + 1, smem, t), );
    PH128(0, 1, 1, 0, 0,
          if (st) stA128(A, m0, K, k1 + 1, 0, smem, t),
          { if (st) { VM4_; } else { VM0_; } });
    PH128(49152, 0, 0, 1, 1,
          if (st) stA128(A, m0, K, k1 + 1, 1, smem, t), );
    PH128(49152, 0, 1, 0, 1, , );
    PH128(49152, 1, 0, 1, 0,
          if (st) stB128(B, n0, K, k1 + 2, smem, t), );
    PH128(49152, 1, 1, 0, 0, ,
          { if (st) { VM2_; } });
  }

  float* slab = (float*)(smem + wv * 4352);
#pragma unroll
  for (int m = 0; m < 4; ++m) {
#pragma unroll
    for (int n = 0; n < 4; ++n)
#pragma unroll
      for (int j = 0; j < 4; ++j)
        slab[(fq * 4 + j) * 68 + n * 16 + fr] = acc[m][n][j];
    int rg0 = m0 + wm * 64 + m * 16;
#pragma unroll
    for (int it = 0; it < 4; ++it) {
      int u = it * 64 + lane;
      int row = u >> 4, seg = u & 15;
      float4 v = *(const float4*)&slab[row * 68 + seg * 4];
      int col = n0 + wn * 64 + seg * 4;
      float4 b4 = *(const float4*)&bias[col];
      v.x += b4.x; v.y += b4.y; v.z += b4.z; v.w += b4.w;
      if (relu) {
        v.x = fmaxf(v.x, 0.f); v.y = fmaxf(v.y, 0.f);
        v.z = fmaxf(v.z, 0.f); v.w = fmaxf(v.w, 0.f);
      }
      size_t idx = (size_t)(rg0 + row) * N + col;
      if (resid) {
        float4 r4 = *(const float4*)&resid[idx];
        v.x += r4.x; v.y += r4.y; v.z += r4.z; v.w += r4.w;
      } else if (residb) {
        ushort4 r4 = *(const ushort4*)&residb[idx];
        v.x += bf2f(r4.x); v.y += bf2f(r4.y); v.z += bf2f(r4.z); v.w += bf2f(r4.w);
      }
      if (Cf) {
        *(float4*)&Cf[idx] = v;
      } else {
        ushort4 ob;
        ob.x = f2bf(v.x); ob.y = f2bf(v.y); ob.z = f2bf(v.z); ob.w = f2bf(v.w);
        *(ushort4*)&Cb[idx] = ob;
      }
    }
  }
}

// ---------------------------------------------------------------------------
// V transpose: qkvb V-part -> vtb [(bh*64 + d)][s].
// ---------------------------------------------------------------------------
__global__ __launch_bounds__(256)
void vtrans_kernel(const unsigned short* __restrict__ qkvb, unsigned short* __restrict__ vtb) {
  __shared__ __align__(16) unsigned short tile[64][64];
  const int st = blockIdx.x;
  const int bh = blockIdx.y;
  const int b = bh >> 4, h = bh & 15;
  const int t = threadIdx.x;
#pragma unroll
  for (int p = 0; p < 2; ++p) {
    int item = p * 256 + t;
    int r = item >> 3, c8 = item & 7;
    const unsigned short* src =
        qkvb + (size_t)(b * SEQ + st * 64 + r) * (3 * DMODEL) + 2048 + h * 64 + c8 * 8;
    *(uint4*)&tile[r][(c8 ^ (r & 7)) * 8] = *(const uint4*)src;
  }
  __syncthreads();
#pragma unroll
  for (int p = 0; p < 2; ++p) {
    int item = p * 256 + t;
    int d = item & 63, s8 = item >> 6;
    unsigned short v[8];
#pragma unroll
    for (int e = 0; e < 8; ++e) {
      int s = s8 * 8 + e;
      v[e] = tile[s][(((d >> 3) ^ (s & 7)) * 8) + (d & 7)];
    }
    uint4 u;
    u.x = (unsigned int)v[0] | ((unsigned int)v[1] << 16);
    u.y = (unsigned int)v[2] | ((unsigned int)v[3] << 16);
    u.z = (unsigned int)v[4] | ((unsigned int)v[5] << 16);
    u.w = (unsigned int)v[6] | ((unsigned int)v[7] << 16);
    *(uint4*)(vtb + ((size_t)bh * 64 + d) * SEQ + st * 64 + s8 * 8) = u;
  }
}

// ---------------------------------------------------------------------------
// MFMA flash attention v5 (round-9 structure, best measured).
// ---------------------------------------------------------------------------
__global__ __launch_bounds__(512, 4)
void attn_kernel(const unsigned short* __restrict__ qkv, const unsigned short* __restrict__ vtb,
                 unsigned short* __restrict__ ctxb) {
  __shared__ __align__(16) unsigned short Ks[2][64][64];
  __shared__ __align__(16) unsigned short Vts[2][64][64];
  __shared__ __align__(16) unsigned short Slab[8][32][64];

  const int t = threadIdx.x;
  const int lane = t & 63;
  const int wq = t >> 6;
  const int l31 = lane & 31;
  const int hi1 = lane >> 5;
  const int bid = blockIdx.x;
  const int bh = bid & 63;
  const int qt = bid >> 6;
  const int b = bh >> 4, h = bh & 15;
  const int q0 = qt * 256;

  const size_t RS = 3 * DMODEL;
  const unsigned short* qb = qkv + (size_t)b * SEQ * RS + h * DHEAD;
  const unsigned short* kb = qb + DMODEL;

  bf16x8 qf[4];
  {
    const unsigned short* qrow = qb + (size_t)(q0 + wq * 32 + l31) * RS;
#pragma unroll
    for (int s = 0; s < 4; ++s)
      qf[s] = *(const bf16x8*)(qrow + s * 16 + hi1 * 8);
  }

  const unsigned short* kgl =
      kb + (size_t)(wq * 8 + (lane >> 3)) * RS + ((lane & 7) ^ (lane >> 3)) * 8;
  const unsigned short* vgl =
      vtb + ((size_t)bh * 64 + wq * 8 + (lane >> 3)) * SEQ + ((lane & 7) ^ (lane >> 3)) * 8;

  f32x16 oacc[2] = {};
  float lacc = 0.f;

  gload16(kgl, (char*)&Ks[0][wq * 8][0]);
  gload16(vgl, (char*)&Vts[0][wq * 8][0]);
  __syncthreads();

  const float C = 0.18033688011112042f;   // 0.125 * log2(e)

  for (int kt = 0; kt < NT; ++kt) {
    const int cur = kt & 1;
    if (kt + 1 < NT) {
      gload16(kgl + (size_t)(kt + 1) * 64 * RS, (char*)&Ks[cur ^ 1][wq * 8][0]);
      gload16(vgl + (size_t)(kt + 1) * 64, (char*)&Vts[cur ^ 1][wq * 8][0]);
    }

    f32x16 sacc[2] = {};
    __builtin_amdgcn_s_setprio(1);
#pragma unroll
    for (int s = 0; s < 4; ++s) {
#pragma unroll
      for (int kvt = 0; kvt < 2; ++kvt) {
        int row = kvt * 32 + l31;
        bf16x8 kf = *(const bf16x8*)&Ks[cur][row][(((2 * s + hi1) ^ (row & 7)) * 8)];
        sacc[kvt] = __builtin_amdgcn_mfma_f32_32x32x16_bf16(kf, qf[s], sacc[kvt], 0, 0, 0);
      }
    }
    __builtin_amdgcn_s_setprio(0);

#pragma unroll
    for (int kvt = 0; kvt < 2; ++kvt) {
      float p[16];
#pragma unroll
      for (int r = 0; r < 16; ++r) p[r] = fexp2(sacc[kvt][r] * C);
      float ps = 0.f;
#pragma unroll
      for (int r = 0; r < 16; ++r) ps += p[r];
      lacc += ps;
#pragma unroll
      for (int half = 0; half < 2; ++half) {
        const int lo = half * 8;
        unsigned int x0 = cvtpk(p[lo + 0], p[lo + 1]);
        unsigned int x1 = cvtpk(p[lo + 2], p[lo + 3]);
        unsigned int y0 = cvtpk(p[lo + 4], p[lo + 5]);
        unsigned int y1 = cvtpk(p[lo + 6], p[lo + 7]);
        plswap(x0, y0);
        plswap(x1, y1);
        bf16x8 pa = __builtin_bit_cast(bf16x8, (u32x4){x0, x1, y0, y1});
        const int s2 = kvt * 2 + half;
        __builtin_amdgcn_s_setprio(1);
#pragma unroll
        for (int dt = 0; dt < 2; ++dt) {
          int vrow = dt * 32 + l31;
          bf16x8 vf = *(const bf16x8*)&Vts[cur][vrow][(((2 * s2 + hi1) ^ (vrow & 7)) * 8)];
          oacc[dt] = __builtin_amdgcn_mfma_f32_32x32x16_bf16(pa, vf, oacc[dt], 0, 0, 0);
        }
        __builtin_amdgcn_s_setprio(0);
      }
    }
    __syncthreads();
  }

  lacc += __shfl_xor(lacc, 32);
  float inv = 1.0f / lacc;

  float iv[16];
#pragma unroll
  for (int r = 0; r < 16; ++r)
    iv[r] = __shfl(inv, (r & 3) + 8 * (r >> 2) + 4 * hi1);

#pragma unroll
  for (int dt = 0; dt < 2; ++dt) {
    const int chunk = dt * 4 + (l31 >> 3);
    const int e7 = l31 & 7;
#pragma unroll
    for (int r = 0; r < 16; ++r) {
      int qp = (r & 3) + 8 * (r >> 2) + 4 * hi1;
      Slab[wq][qp][((chunk ^ (qp & 7)) * 8) + e7] = f2bf(oacc[dt][r] * iv[r]);
    }
  }
#pragma unroll
  for (int it = 0; it < 4; ++it) {
    int u = it * 64 + lane;
    int row = u >> 3, s = u & 7;
    uint4 v = *(const uint4*)&Slab[wq][row][((s ^ (row & 7)) * 8)];
    *(uint4*)(ctxb + (size_t)(b * SEQ + q0 + wq * 32 + row) * DMODEL + h * DHEAD + s * 8) = v;
  }
}

// ---------------------------------------------------------------------------
// LayerNorm: input f32 (Zf) or bf16 (Zb); outputs f32 (Yf) and/or bf16 (Yb).
// ---------------------------------------------------------------------------
__global__ __launch_bounds__(256)
void ln_kernel(const float* __restrict__ Zf, const unsigned short* __restrict__ Zb,
               const float* __restrict__ g, const float* __restrict__ bta,
               float* __restrict__ Yf, unsigned short* __restrict__ Yb) {
  const int row = blockIdx.x;
  float4 v;
  if (Zf) {
    v = ((const float4*)(Zf + (size_t)row * DMODEL))[threadIdx.x];
  } else {
    ushort4 u = ((const ushort4*)(Zb + (size_t)row * DMODEL))[threadIdx.x];
    v.x = bf2f(u.x); v.y = bf2f(u.y); v.z = bf2f(u.z); v.w = bf2f(u.w);
  }
  float s = v.x + v.y + v.z + v.w;
  float ss = fmaf(v.x, v.x, fmaf(v.y, v.y, fmaf(v.z, v.z, v.w * v.w)));
#pragma unroll
  for (int o = 32; o >= 1; o >>= 1) {
    s += __shfl_xor(s, o);
    ss += __shfl_xor(ss, o);
  }
  __shared__ float red[8];
  int w = threadIdx.x >> 6;
  if ((threadIdx.x & 63) == 0) { red[w] = s; red[4 + w] = ss; }
  __syncthreads();
  s = red[0] + red[1] + red[2] + red[3];
  ss = red[4] + red[5] + red[6] + red[7];
  float mu = s * (1.0f / DMODEL);
  float var = ss * (1.0f / DMODEL) - mu * mu;
  float rs = rsqrtf(var + LNEPS);
  float4 gg = ((const float4*)g)[threadIdx.x];
  float4 bb = ((const float4*)bta)[threadIdx.x];
  float4 o;
  o.x = (v.x - mu) * rs * gg.x + bb.x;
  o.y = (v.y - mu) * rs * gg.y + bb.y;
  o.z = (v.z - mu) * rs * gg.z + bb.z;
  o.w = (v.w - mu) * rs * gg.w + bb.w;
  if (Yf) ((float4*)(Yf + (size_t)row * DMODEL))[threadIdx.x] = o;
  if (Yb) {
    ushort4 ob;
    ob.x = f2bf(o.x); ob.y = f2bf(o.y); ob.z = f2bf(o.z); ob.w = f2bf(o.w);
    ((ushort4*)(Yb + (size_t)row * DMODEL))[threadIdx.x] = ob;
  }
}

// ---------------------------------------------------------------------------
extern "C" void kernel_launch(void* const* d_in, const int* in_sizes, int n_in,
                              void* d_out, int out_size, void* d_ws, size_t ws_size,
                              hipStream_t stream) {
  const int* tokens       = (const int*)d_in[0];
  const float* emb        = (const float*)d_in[1];
  const float* in_proj_w  = (const float*)d_in[2];
  const float* in_proj_b  = (const float*)d_in[3];
  const float* out_proj_w = (const float*)d_in[4];
  const float* out_proj_b = (const float*)d_in[5];
  const float* w1         = (const float*)d_in[6];
  const float* b1         = (const float*)d_in[7];
  const float* w2         = (const float*)d_in[8];
  const float* b2         = (const float*)d_in[9];
  const float* g1         = (const float*)d_in[10];
  const float* beta1      = (const float*)d_in[11];
  const float* g2         = (const float*)d_in[12];
  const float* beta2      = (const float*)d_in[13];
  float* out = (float*)d_out;

  char* ws = (char*)d_ws;
  const size_t MB = 1ull << 20;
  // Memory plan (peak 184 MiB), lifetimes:
  //   inwb [0,6) outwb [6,8) w1b [8,16) w2b [16,24)  bf16 weights (whole pass)
  //   y2    [24,56)   f32 ff2 out (live ff2..LN2)
  //   xb    [56,72)   bf16 embed out; RESIDUAL for out-proj (live embed..outproj)
  //   qkvb  [72,120)  bf16 qkv (live qkv-gemm..attn)
  //   hpre_b[72,88)   bf16 out-proj out (reuses qkvb, dead after attn)
  //   hb    [104,120) bf16 LN1 out (reuses qkvb tail; ff1 A + ff2 residual)
  //   vtb   [120,136) bf16 V^T (live vtrans..attn)
  //   ctxb  [136,152) bf16 attn out (live attn..out-proj)
  //   ffbb  [120,184) bf16 relu(ff1) (live ff1..ff2; vtb/ctxb dead by then)
  unsigned short* inwb  = (unsigned short*)(ws + 0 * MB);
  unsigned short* outwb = (unsigned short*)(ws + 6 * MB);
  unsigned short* w1b   = (unsigned short*)(ws + 8 * MB);
  unsigned short* w2b   = (unsigned short*)(ws + 16 * MB);
  float* y2             = (float*)(ws + 24 * MB);
  unsigned short* xb    = (unsigned short*)(ws + 56 * MB);
  unsigned short* qkvb  = (unsigned short*)(ws + 72 * MB);
  unsigned short* hpre_b = (unsigned short*)(ws + 72 * MB);
  unsigned short* hb    = (unsigned short*)(ws + 104 * MB);
  unsigned short* vtb   = (unsigned short*)(ws + 120 * MB);
  unsigned short* ctxb  = (unsigned short*)(ws + 136 * MB);
  unsigned short* ffbb  = (unsigned short*)(ws + 120 * MB);

  const size_t GLDSP  = 131072;   // gemm8p: 128 KB
  const size_t GLDSPN = 98304;    // gemm8p128: 96 KB

  // 1. embedding + positional encoding -> xb (bf16 only)
  embed_kernel<<<(MROWS * (DMODEL / 2) + 255) / 256, 256, 0, stream>>>(tokens, emb, xb);
  cvt4_kernel<<<12288, 256, 0, stream>>>(in_proj_w, out_proj_w, w1, w2,
                                         inwb, outwb, w1b, w2b);
  // 2. qkv = x @ in_proj_w^T + b  (bf16 out)   [384 blocks, 8-phase 256x256]
  gemm8p<<<(MROWS / 256) * (3 * DMODEL / 256), 512, GLDSP, stream>>>(
      xb, inwb, in_proj_b, nullptr, nullptr, qkvb, MROWS, 3 * DMODEL, DMODEL, 0);
  // 3. V^T pre-transpose
  vtrans_kernel<<<dim3(SEQ / 64, BATCH * NH), 256, 0, stream>>>(qkvb, vtb);
  // 4. flash attention v5 -> ctxb (bf16)   [512 blocks]
  attn_kernel<<<(SEQ / 256) * (BATCH * NH), 512, 0, stream>>>(qkvb, vtb, ctxb);
  // 5. hpre = ctx @ out_proj_w^T + b + xb  (bf16 out)   [256 blocks]
  gemm8p128<<<(MROWS / 256) * (DMODEL / 128), 512, GLDSPN, stream>>>(
      ctxb, outwb, out_proj_b, nullptr, xb, nullptr, hpre_b, MROWS, DMODEL, DMODEL, 0);
  // 6. hb = LN1(hpre)  (bf16 in, bf16 out)
  ln_kernel<<<MROWS, 256, 0, stream>>>(nullptr, hpre_b, g1, beta1, nullptr, hb);
  // 7. ffb = relu(hb @ w1^T + b1)  (bf16 out)   [512 blocks, 8-phase 256x256]
  gemm8p<<<(MROWS / 256) * (DFF / 256), 512, GLDSP, stream>>>(
      hb, w1b, b1, nullptr, nullptr, ffbb, MROWS, DFF, DMODEL, 1);
  // 8. y2 = ffb @ w2^T + b2 + hb  (f32 out)   [256 blocks]
  gemm8p128<<<(MROWS / 256) * (DMODEL / 128), 512, GLDSPN, stream>>>(
      ffbb, w2b, b2, nullptr, hb, y2, nullptr, MROWS, DMODEL, DFF, 0);
  // 9. out = LN2(y2)  (f32 in, f32 out)
  ln_kernel<<<MROWS, 256, 0, stream>>>(y2, nullptr, g2, beta2, out, nullptr);
}

// Round 14
// 385.240 us; speedup vs baseline: 1.0584x; 1.0167x over previous
//
#include <hip/hip_runtime.h>
#include <math.h>

#define DMODEL 1024
#define NH 16
#define DHEAD 64
#define DFF 4096
#define BATCH 4
#define SEQ 2048
#define MROWS (BATCH * SEQ)   // 8192
#define LNEPS 1e-5f
#define NT (SEQ / 64)         // 32 kv tiles

typedef __attribute__((ext_vector_type(8))) short bf16x8;
typedef __attribute__((ext_vector_type(4))) float f32x4;
typedef __attribute__((ext_vector_type(16))) float f32x16;
typedef __attribute__((ext_vector_type(4))) unsigned int u32x4;

__device__ inline unsigned short f2bf(float f) {
  unsigned int u = __float_as_uint(f);
  unsigned int r = (u + 0x7fffu + ((u >> 16) & 1u)) >> 16;  // RNE
  return (unsigned short)r;
}
__device__ inline float bf2f(unsigned short b) {
  return __uint_as_float(((unsigned int)b) << 16);
}

__device__ inline void gload16(const unsigned short* g, char* l) {
  __builtin_amdgcn_global_load_lds(
      (const __attribute__((address_space(1))) unsigned int*)g,
      (__attribute__((address_space(3))) unsigned int*)l, 16, 0, 0);
}

__device__ inline float fexp2(float x) {
  float r;
  asm("v_exp_f32 %0, %1" : "=v"(r) : "v"(x));
  return r;
}
__device__ inline unsigned int cvtpk(float lo, float hi) {
  unsigned int r;
  asm("v_cvt_pk_bf16_f32 %0, %1, %2" : "=v"(r) : "v"(lo), "v"(hi));
  return r;
}
__device__ inline void plswap(unsigned int& a, unsigned int& b) {
  asm("v_permlane32_swap_b32 %0, %1" : "+v"(a), "+v"(b));
}

// ---------------------------------------------------------------------------
// Fused prologue: blocks [0,16384) do embedding+pos-enc -> bf16 xb;
// blocks [16384, 28672) do the 4-weight fp32->bf16 conversion.
// ---------------------------------------------------------------------------
__global__ __launch_bounds__(256)
void prep_kernel(const int* __restrict__ tokens, const float* __restrict__ emb,
                 unsigned short* __restrict__ Xb,
                 const float* __restrict__ a, const float* __restrict__ b,
                 const float* __restrict__ c, const float* __restrict__ d,
                 unsigned short* __restrict__ oa, unsigned short* __restrict__ ob,
                 unsigned short* __restrict__ oc, unsigned short* __restrict__ od) {
  const int bid = blockIdx.x;
  if (bid < 16384) {
    const int HALF = DMODEL / 2;
    int idx = bid * 256 + threadIdx.x;
    int row = idx / HALF;
    int j = idx - row * HALF;
    int s = row & (SEQ - 1);
    int tok = tokens[row];
    float2 e = ((const float2*)(emb + (size_t)tok * DMODEL))[j];
    float denom = powf(10000.0f, (2.0f * (float)(2 * j)) / (float)DMODEL);
    float ang = (float)s / denom;
    float sn, cs;
    sincosf(ang, &sn, &cs);
    ushort2 o2;
    o2.x = f2bf(e.x + sn);
    o2.y = f2bf(e.y + cs);
    ((ushort2*)(Xb + (size_t)row * DMODEL))[j] = o2;
  } else {
    int i = (bid - 16384) * 256 + threadIdx.x;
    const float* src; unsigned short* dst; int off;
    if (i < 786432)       { src = a; dst = oa; off = 0; }
    else if (i < 1048576) { src = b; dst = ob; off = 786432; }
    else if (i < 2097152) { src = c; dst = oc; off = 1048576; }
    else                  { src = d; dst = od; off = 2097152; }
    int j = i - off;
    float4 v = ((const float4*)src)[j];
    ushort4 o;
    o.x = f2bf(v.x); o.y = f2bf(v.y); o.z = f2bf(v.z); o.w = f2bf(v.w);
    ((ushort4*)dst)[j] = o;
  }
}

// ---------------------------------------------------------------------------
// gemm8p: 8-phase 256x256 GEMM (round-10 structure; ff1 only now).
// ---------------------------------------------------------------------------
__device__ inline void sthalf8(const unsigned short* G, int grow0, int K, int kt,
                               char* smem_, int isB, int half, int t) {
  char* dst = smem_ + ((kt & 1) * 65536) + isB * 32768 + half * 16384;
#pragma unroll
  for (int i = 0; i < 2; ++i) {
    int g = i * 512 + t;
    int r = g >> 3, sl = g & 7;
    int c = sl ^ (r & 7);
    gload16(G + (size_t)(grow0 + half * 128 + r) * K + kt * 64 + c * 8, dst + g * 16);
  }
}

#define VM4_ asm volatile("s_waitcnt vmcnt(4)" ::: "memory")
#define VM2_ asm volatile("s_waitcnt vmcnt(2)" ::: "memory")
#define VM0_ asm volatile("s_waitcnt vmcnt(0)" ::: "memory")

#define PHASE8(bufofs, MG, NP, LA, LB, STAGE_STMT, WAIT_STMT)                   \
  {                                                                             \
    if (LA) {                                                                   \
      _Pragma("unroll") for (int m = 0; m < 4; ++m) {                           \
        int arow = wm * 128 + (MG) * 64 + m * 16 + fr;                          \
        _Pragma("unroll") for (int ks = 0; ks < 2; ++ks)                        \
          af[m][ks] = *(const bf16x8*)(smem + (bufofs) + arow * 128 +           \
                        (((ks * 4 + fq) ^ (arow & 7)) * 16));                   \
      }                                                                         \
    }                                                                           \
    if (LB) {                                                                   \
      _Pragma("unroll") for (int nn = 0; nn < 2; ++nn) {                        \
        int n = (NP) * 2 + nn;                                                  \
        int brow = wn * 64 + n * 16 + fr;                                       \
        _Pragma("unroll") for (int ks = 0; ks < 2; ++ks)                        \
          bf[(NP) * 2 + nn][ks] = *(const bf16x8*)(smem + (bufofs) + 32768 +    \
                        brow * 128 + (((ks * 4 + fq) ^ (brow & 7)) * 16));      \
      }                                                                         \
    }                                                                           \
    STAGE_STMT;                                                                 \
    __builtin_amdgcn_sched_barrier(0);                                          \
    __builtin_amdgcn_s_barrier();                                               \
    asm volatile("s_waitcnt lgkmcnt(0)" ::: "memory");                          \
    __builtin_amdgcn_sched_barrier(0);                                          \
    __builtin_amdgcn_s_setprio(1);                                              \
    _Pragma("unroll") for (int m = 0; m < 4; ++m)                               \
      _Pragma("unroll") for (int nn = 0; nn < 2; ++nn)                          \
        _Pragma("unroll") for (int ks = 0; ks < 2; ++ks)                        \
          acc[(MG) * 4 + m][(NP) * 2 + nn] =                                    \
              __builtin_amdgcn_mfma_f32_16x16x32_bf16(                          \
                  af[m][ks], bf[(NP) * 2 + nn][ks],                             \
                  acc[(MG) * 4 + m][(NP) * 2 + nn], 0, 0, 0);                   \
    __builtin_amdgcn_s_setprio(0);                                              \
    WAIT_STMT;                                                                  \
    __builtin_amdgcn_sched_barrier(0);                                          \
    __builtin_amdgcn_s_barrier();                                               \
    __builtin_amdgcn_sched_barrier(0);                                          \
  }

__global__ __launch_bounds__(512, 2)
void gemm8p(const unsigned short* __restrict__ A, const unsigned short* __restrict__ B,
            const float* __restrict__ bias, const float* __restrict__ resid,
            float* __restrict__ Cf, unsigned short* __restrict__ Cb,
            int M, int N, int K, int relu) {
  extern __shared__ char smem[];   // 131072: 2 bufs x (A 32K + B 32K)

  const int t = threadIdx.x;
  const int lane = t & 63;
  const int wv = t >> 6;
  const int wm = wv >> 2;
  const int wn = wv & 3;
  const int fr = lane & 15;
  const int fq = lane >> 4;

  const int nwg = gridDim.x;
  const int orig = blockIdx.x;
  const int q8 = nwg >> 3;
  const int wgid = (orig & 7) * q8 + (orig >> 3);
  const int stid = wgid >> 2, within = wgid & 3;
  const int sm = within & 1, sn = within >> 1;
  const int Msup = M >> 9;
  const int stm = stid % Msup, stn = stid / Msup;
  const int m0 = (stm * 2 + sm) * 256;
  const int n0 = (stn * 2 + sn) * 256;

  f32x4 acc[8][4];
#pragma unroll
  for (int m = 0; m < 8; ++m)
#pragma unroll
    for (int n = 0; n < 4; ++n) acc[m][n] = (f32x4){0.f, 0.f, 0.f, 0.f};

  const int nk = K / 64;
  const int nj = nk / 2;

  sthalf8(A, m0, K, 0, smem, 0, 0, t);
  sthalf8(A, m0, K, 0, smem, 0, 1, t);
  sthalf8(B, n0, K, 0, smem, 1, 0, t);
  sthalf8(B, n0, K, 0, smem, 1, 1, t);
  sthalf8(B, n0, K, 1, smem, 1, 0, t);
  sthalf8(B, n0, K, 1, smem, 1, 1, t);
  VM4_;
  __builtin_amdgcn_sched_barrier(0);
  __builtin_amdgcn_s_barrier();
  __builtin_amdgcn_sched_barrier(0);

  bf16x8 af[4][2];
  bf16x8 bf[4][2];

  for (int j = 0; j < nj; ++j) {
    const bool st = (j + 1 < nj);
    PHASE8(0, 0, 0, 1, 1, sthalf8(A, m0, K, 2 * j + 1, smem, 0, 0, t), );
    PHASE8(0, 0, 1, 0, 1, sthalf8(A, m0, K, 2 * j + 1, smem, 0, 1, t), );
    PHASE8(0, 1, 1, 1, 0,
           if (st) sthalf8(B, n0, K, 2 * j + 2, smem, 1, 0, t), );
    PHASE8(0, 1, 0, 0, 0,
           if (st) sthalf8(B, n0, K, 2 * j + 2, smem, 1, 1, t),
           { if (st) { VM4_; } else { VM0_; } });
    PHASE8(65536, 0, 0, 1, 1,
           if (st) sthalf8(A, m0, K, 2 * j + 2, smem, 0, 0, t), );
    PHASE8(65536, 0, 1, 0, 1,
           if (st) sthalf8(A, m0, K, 2 * j + 2, smem, 0, 1, t), );
    PHASE8(65536, 1, 1, 1, 0,
           if (st) sthalf8(B, n0, K, 2 * j + 3, smem, 1, 0, t), );
    PHASE8(65536, 1, 0, 0, 0,
           if (st) sthalf8(B, n0, K, 2 * j + 3, smem, 1, 1, t),
           { if (st) { VM4_; } });
  }

  float* slab = (float*)(smem + wv * 4352);
#pragma unroll
  for (int m = 0; m < 8; ++m) {
#pragma unroll
    for (int n = 0; n < 4; ++n)
#pragma unroll
      for (int j = 0; j < 4; ++j)
        slab[(fq * 4 + j) * 68 + n * 16 + fr] = acc[m][n][j];
    int rg0 = m0 + wm * 128 + m * 16;
#pragma unroll
    for (int it = 0; it < 4; ++it) {
      int u = it * 64 + lane;
      int row = u >> 4, seg = u & 15;
      float4 v = *(const float4*)&slab[row * 68 + seg * 4];
      int col = n0 + wn * 64 + seg * 4;
      float4 b4 = *(const float4*)&bias[col];
      v.x += b4.x; v.y += b4.y; v.z += b4.z; v.w += b4.w;
      if (relu) {
        v.x = fmaxf(v.x, 0.f); v.y = fmaxf(v.y, 0.f);
        v.z = fmaxf(v.z, 0.f); v.w = fmaxf(v.w, 0.f);
      }
      size_t idx = (size_t)(rg0 + row) * N + col;
      if (resid) {
        float4 r4 = *(const float4*)&resid[idx];
        v.x += r4.x; v.y += r4.y; v.z += r4.z; v.w += r4.w;
      }
      if (Cf) {
        *(float4*)&Cf[idx] = v;
      } else {
        ushort4 ob;
        ob.x = f2bf(v.x); ob.y = f2bf(v.y); ob.z = f2bf(v.z); ob.w = f2bf(v.w);
        *(ushort4*)&Cb[idx] = ob;
      }
    }
  }
}

// ---------------------------------------------------------------------------
// gemm8p128: fine-phase schedule at BM=256, BN=128 (qkv, out-proj, ff2).
// Residual f32 (resid) or bf16 (residb); output f32 (Cf) or bf16 (Cb).
// ---------------------------------------------------------------------------
__device__ inline void stA128(const unsigned short* G, int m0, int K, int kt,
                              int half, char* smem_, int t) {
  char* dst = smem_ + ((kt & 1) * 49152) + half * 16384;
#pragma unroll
  for (int i = 0; i < 2; ++i) {
    int g = i * 512 + t;
    int r = g >> 3, sl = g & 7;
    int c = sl ^ (r & 7);
    gload16(G + (size_t)(m0 + half * 128 + r) * K + kt * 64 + c * 8, dst + g * 16);
  }
}
__device__ inline void stB128(const unsigned short* G, int n0, int K, int kt,
                              char* smem_, int t) {
  char* dst = smem_ + ((kt & 1) * 49152) + 32768;
#pragma unroll
  for (int i = 0; i < 2; ++i) {
    int g = i * 512 + t;
    int r = g >> 3, sl = g & 7;
    int c = sl ^ (r & 7);
    gload16(G + (size_t)(n0 + r) * K + kt * 64 + c * 8, dst + g * 16);
  }
}

#define PH128(bufofs, MG, NP, LA, LB, STAGE_STMT, WAIT_STMT)                    \
  {                                                                             \
    if (LA) {                                                                   \
      _Pragma("unroll") for (int mm = 0; mm < 2; ++mm) {                        \
        int arow = wm * 64 + ((MG) * 2 + mm) * 16 + fr;                         \
        _Pragma("unroll") for (int ks = 0; ks < 2; ++ks)                        \
          af[mm][ks] = *(const bf16x8*)(smem + (bufofs) + arow * 128 +          \
                        (((ks * 4 + fq) ^ (arow & 7)) * 16));                   \
      }                                                                         \
    }                                                                           \
    if (LB) {                                                                   \
      _Pragma("unroll") for (int nn = 0; nn < 2; ++nn) {                        \
        int n = (NP) * 2 + nn;                                                  \
        int brow = wn * 64 + n * 16 + fr;                                       \
        _Pragma("unroll") for (int ks = 0; ks < 2; ++ks)                        \
          bf[(NP) * 2 + nn][ks] = *(const bf16x8*)(smem + (bufofs) + 32768 +    \
                        brow * 128 + (((ks * 4 + fq) ^ (brow & 7)) * 16));      \
      }                                                                         \
    }                                                                           \
    STAGE_STMT;                                                                 \
    __builtin_amdgcn_sched_barrier(0);                                          \
    __builtin_amdgcn_s_barrier();                                               \
    asm volatile("s_waitcnt lgkmcnt(0)" ::: "memory");                          \
    __builtin_amdgcn_sched_barrier(0);                                          \
    __builtin_amdgcn_s_setprio(1);                                              \
    _Pragma("unroll") for (int mm = 0; mm < 2; ++mm)                            \
      _Pragma("unroll") for (int nn = 0; nn < 2; ++nn)                          \
        _Pragma("unroll") for (int ks = 0; ks < 2; ++ks)                        \
          acc[(MG) * 2 + mm][(NP) * 2 + nn] =                                   \
              __builtin_amdgcn_mfma_f32_16x16x32_bf16(                          \
                  af[mm][ks], bf[(NP) * 2 + nn][ks],                            \
                  acc[(MG) * 2 + mm][(NP) * 2 + nn], 0, 0, 0);                  \
    __builtin_amdgcn_s_setprio(0);                                              \
    WAIT_STMT;                                                                  \
    __builtin_amdgcn_sched_barrier(0);                                          \
    __builtin_amdgcn_s_barrier();                                               \
    __builtin_amdgcn_sched_barrier(0);                                          \
  }

__global__ __launch_bounds__(512, 2)
void gemm8p128(const unsigned short* __restrict__ A, const unsigned short* __restrict__ B,
               const float* __restrict__ bias, const float* __restrict__ resid,
               const unsigned short* __restrict__ residb,
               float* __restrict__ Cf, unsigned short* __restrict__ Cb,
               int M, int N, int K, int relu) {
  extern __shared__ char smem[];   // 98304: 2 bufs x (A 32K + B 16K)

  const int t = threadIdx.x;
  const int lane = t & 63;
  const int wv = t >> 6;
  const int wm = wv >> 1;
  const int wn = wv & 1;
  const int fr = lane & 15;
  const int fq = lane >> 4;

  const int nwg = gridDim.x;
  const int orig = blockIdx.x;
  const int q8 = nwg >> 3;
  const int wgid = (orig & 7) * q8 + (orig >> 3);
  const int stid = wgid >> 2, within = wgid & 3;
  const int sm = within & 1, sn = within >> 1;
  const int Msup = M >> 9;
  const int stm = stid % Msup, stn = stid / Msup;
  const int m0 = (stm * 2 + sm) * 256;
  const int n0 = (stn * 2 + sn) * 128;

  f32x4 acc[4][4];
#pragma unroll
  for (int m = 0; m < 4; ++m)
#pragma unroll
    for (int n = 0; n < 4; ++n) acc[m][n] = (f32x4){0.f, 0.f, 0.f, 0.f};

  const int nk = K / 64;
  const int nj = nk / 2;

  stA128(A, m0, K, 0, 0, smem, t);
  stA128(A, m0, K, 0, 1, smem, t);
  stB128(B, n0, K, 0, smem, t);
  stB128(B, n0, K, 1, smem, t);
  VM2_;
  __builtin_amdgcn_sched_barrier(0);
  __builtin_amdgcn_s_barrier();
  __builtin_amdgcn_sched_barrier(0);

  bf16x8 af[2][2];
  bf16x8 bf[4][2];

  for (int j = 0; j < nj; ++j) {
    const bool st = (j + 1 < nj);
    const int k1 = 2 * j + 1;
    PH128(0, 0, 0, 1, 1, stA128(A, m0, K, k1, 0, smem, t), );
    PH128(0, 0, 1, 0, 1, stA128(A, m0, K, k1, 1, smem, t), );
    PH128(0, 1, 0, 1, 0,
          if (st) stB128(B, n0, K, k1 + 1, smem, t), );
    PH128(0, 1, 1, 0, 0,
          if (st) stA128(A, m0, K, k1 + 1, 0, smem, t),
          { if (st) { VM4_; } else { VM0_; } });
    PH128(49152, 0, 0, 1, 1,
          if (st) stA128(A, m0, K, k1 + 1, 1, smem, t), );
    PH128(49152, 0, 1, 0, 1, , );
    PH128(49152, 1, 0, 1, 0,
          if (st) stB128(B, n0, K, k1 + 2, smem, t), );
    PH128(49152, 1, 1, 0, 0, ,
          { if (st) { VM2_; } });
  }

  float* slab = (float*)(smem + wv * 4352);
#pragma unroll
  for (int m = 0; m < 4; ++m) {
#pragma unroll
    for (int n = 0; n < 4; ++n)
#pragma unroll
      for (int j = 0; j < 4; ++j)
        slab[(fq * 4 + j) * 68 + n * 16 + fr] = acc[m][n][j];
    int rg0 = m0 + wm * 64 + m * 16;
#pragma unroll
    for (int it = 0; it < 4; ++it) {
      int u = it * 64 + lane;
      int row = u >> 4, seg = u & 15;
      float4 v = *(const float4*)&slab[row * 68 + seg * 4];
      int col = n0 + wn * 64 + seg * 4;
      float4 b4 = *(const float4*)&bias[col];
      v.x += b4.x; v.y += b4.y; v.z += b4.z; v.w += b4.w;
      if (relu) {
        v.x = fmaxf(v.x, 0.f); v.y = fmaxf(v.y, 0.f);
        v.z = fmaxf(v.z, 0.f); v.w = fmaxf(v.w, 0.f);
      }
      size_t idx = (size_t)(rg0 + row) * N + col;
      if (resid) {
        float4 r4 = *(const float4*)&resid[idx];
        v.x += r4.x; v.y += r4.y; v.z += r4.z; v.w += r4.w;
      } else if (residb) {
        ushort4 r4 = *(const ushort4*)&residb[idx];
        v.x += bf2f(r4.x); v.y += bf2f(r4.y); v.z += bf2f(r4.z); v.w += bf2f(r4.w);
      }
      if (Cf) {
        *(float4*)&Cf[idx] = v;
      } else {
        ushort4 ob;
        ob.x = f2bf(v.x); ob.y = f2bf(v.y); ob.z = f2bf(v.z); ob.w = f2bf(v.w);
        *(ushort4*)&Cb[idx] = ob;
      }
    }
  }
}

// ---------------------------------------------------------------------------
// V transpose: qkvb V-part -> vtb [(bh*64 + d)][s].
// ---------------------------------------------------------------------------
__global__ __launch_bounds__(256)
void vtrans_kernel(const unsigned short* __restrict__ qkvb, unsigned short* __restrict__ vtb) {
  __shared__ __align__(16) unsigned short tile[64][64];
  const int st = blockIdx.x;
  const int bh = blockIdx.y;
  const int b = bh >> 4, h = bh & 15;
  const int t = threadIdx.x;
#pragma unroll
  for (int p = 0; p < 2; ++p) {
    int item = p * 256 + t;
    int r = item >> 3, c8 = item & 7;
    const unsigned short* src =
        qkvb + (size_t)(b * SEQ + st * 64 + r) * (3 * DMODEL) + 2048 + h * 64 + c8 * 8;
    *(uint4*)&tile[r][(c8 ^ (r & 7)) * 8] = *(const uint4*)src;
  }
  __syncthreads();
#pragma unroll
  for (int p = 0; p < 2; ++p) {
    int item = p * 256 + t;
    int d = item & 63, s8 = item >> 6;
    unsigned short v[8];
#pragma unroll
    for (int e = 0; e < 8; ++e) {
      int s = s8 * 8 + e;
      v[e] = tile[s][(((d >> 3) ^ (s & 7)) * 8) + (d & 7)];
    }
    uint4 u;
    u.x = (unsigned int)v[0] | ((unsigned int)v[1] << 16);
    u.y = (unsigned int)v[2] | ((unsigned int)v[3] << 16);
    u.z = (unsigned int)v[4] | ((unsigned int)v[5] << 16);
    u.w = (unsigned int)v[6] | ((unsigned int)v[7] << 16);
    *(uint4*)(vtb + ((size_t)bh * 64 + d) * SEQ + st * 64 + s8 * 8) = u;
  }
}

// ---------------------------------------------------------------------------
// MFMA flash attention v5 (round-9 structure, best measured).
// ---------------------------------------------------------------------------
__global__ __launch_bounds__(512, 4)
void attn_kernel(const unsigned short* __restrict__ qkv, const unsigned short* __restrict__ vtb,
                 unsigned short* __restrict__ ctxb) {
  __shared__ __align__(16) unsigned short Ks[2][64][64];
  __shared__ __align__(16) unsigned short Vts[2][64][64];
  __shared__ __align__(16) unsigned short Slab[8][32][64];

  const int t = threadIdx.x;
  const int lane = t & 63;
  const int wq = t >> 6;
  const int l31 = lane & 31;
  const int hi1 = lane >> 5;
  const int bid = blockIdx.x;
  const int bh = bid & 63;
  const int qt = bid >> 6;
  const int b = bh >> 4, h = bh & 15;
  const int q0 = qt * 256;

  const size_t RS = 3 * DMODEL;
  const unsigned short* qb = qkv + (size_t)b * SEQ * RS + h * DHEAD;
  const unsigned short* kb = qb + DMODEL;

  bf16x8 qf[4];
  {
    const unsigned short* qrow = qb + (size_t)(q0 + wq * 32 + l31) * RS;
#pragma unroll
    for (int s = 0; s < 4; ++s)
      qf[s] = *(const bf16x8*)(qrow + s * 16 + hi1 * 8);
  }

  const unsigned short* kgl =
      kb + (size_t)(wq * 8 + (lane >> 3)) * RS + ((lane & 7) ^ (lane >> 3)) * 8;
  const unsigned short* vgl =
      vtb + ((size_t)bh * 64 + wq * 8 + (lane >> 3)) * SEQ + ((lane & 7) ^ (lane >> 3)) * 8;

  f32x16 oacc[2] = {};
  float lacc = 0.f;

  gload16(kgl, (char*)&Ks[0][wq * 8][0]);
  gload16(vgl, (char*)&Vts[0][wq * 8][0]);
  __syncthreads();

  const float C = 0.18033688011112042f;   // 0.125 * log2(e)

  for (int kt = 0; kt < NT; ++kt) {
    const int cur = kt & 1;
    if (kt + 1 < NT) {
      gload16(kgl + (size_t)(kt + 1) * 64 * RS, (char*)&Ks[cur ^ 1][wq * 8][0]);
      gload16(vgl + (size_t)(kt + 1) * 64, (char*)&Vts[cur ^ 1][wq * 8][0]);
    }

    f32x16 sacc[2] = {};
    __builtin_amdgcn_s_setprio(1);
#pragma unroll
    for (int s = 0; s < 4; ++s) {
#pragma unroll
      for (int kvt = 0; kvt < 2; ++kvt) {
        int row = kvt * 32 + l31;
        bf16x8 kf = *(const bf16x8*)&Ks[cur][row][(((2 * s + hi1) ^ (row & 7)) * 8)];
        sacc[kvt] = __builtin_amdgcn_mfma_f32_32x32x16_bf16(kf, qf[s], sacc[kvt], 0, 0, 0);
      }
    }
    __builtin_amdgcn_s_setprio(0);

#pragma unroll
    for (int kvt = 0; kvt < 2; ++kvt) {
      float p[16];
#pragma unroll
      for (int r = 0; r < 16; ++r) p[r] = fexp2(sacc[kvt][r] * C);
      float ps = 0.f;
#pragma unroll
      for (int r = 0; r < 16; ++r) ps += p[r];
      lacc += ps;
#pragma unroll
      for (int half = 0; half < 2; ++half) {
        const int lo = half * 8;
        unsigned int x0 = cvtpk(p[lo + 0], p[lo + 1]);
        unsigned int x1 = cvtpk(p[lo + 2], p[lo + 3]);
        unsigned int y0 = cvtpk(p[lo + 4], p[lo + 5]);
        unsigned int y1 = cvtpk(p[lo + 6], p[lo + 7]);
        plswap(x0, y0);
        plswap(x1, y1);
        bf16x8 pa = __builtin_bit_cast(bf16x8, (u32x4){x0, x1, y0, y1});
        const int s2 = kvt * 2 + half;
        __builtin_amdgcn_s_setprio(1);
#pragma unroll
        for (int dt = 0; dt < 2; ++dt) {
          int vrow = dt * 32 + l31;
          bf16x8 vf = *(const bf16x8*)&Vts[cur][vrow][(((2 * s2 + hi1) ^ (vrow & 7)) * 8)];
          oacc[dt] = __builtin_amdgcn_mfma_f32_32x32x16_bf16(pa, vf, oacc[dt], 0, 0, 0);
        }
        __builtin_amdgcn_s_setprio(0);
      }
    }
    __syncthreads();
  }

  lacc += __shfl_xor(lacc, 32);
  float inv = 1.0f / lacc;

  float iv[16];
#pragma unroll
  for (int r = 0; r < 16; ++r)
    iv[r] = __shfl(inv, (r & 3) + 8 * (r >> 2) + 4 * hi1);

#pragma unroll
  for (int dt = 0; dt < 2; ++dt) {
    const int chunk = dt * 4 + (l31 >> 3);
    const int e7 = l31 & 7;
#pragma unroll
    for (int r = 0; r < 16; ++r) {
      int qp = (r & 3) + 8 * (r >> 2) + 4 * hi1;
      Slab[wq][qp][((chunk ^ (qp & 7)) * 8) + e7] = f2bf(oacc[dt][r] * iv[r]);
    }
  }
#pragma unroll
  for (int it = 0; it < 4; ++it) {
    int u = it * 64 + lane;
    int row = u >> 3, s = u & 7;
    uint4 v = *(const uint4*)&Slab[wq][row][((s ^ (row & 7)) * 8)];
    *(uint4*)(ctxb + (size_t)(b * SEQ + q0 + wq * 32 + row) * DMODEL + h * DHEAD + s * 8) = v;
  }
}

// ---------------------------------------------------------------------------
// LayerNorm: input f32 (Zf) or bf16 (Zb); outputs f32 (Yf) and/or bf16 (Yb).
// ---------------------------------------------------------------------------
__global__ __launch_bounds__(256)
void ln_kernel(const float* __restrict__ Zf, const unsigned short* __restrict__ Zb,
               const float* __restrict__ g, const float* __restrict__ bta,
               float* __restrict__ Yf, unsigned short* __restrict__ Yb) {
  const int row = blockIdx.x;
  float4 v;
  if (Zf) {
    v = ((const float4*)(Zf + (size_t)row * DMODEL))[threadIdx.x];
  } else {
    ushort4 u = ((const ushort4*)(Zb + (size_t)row * DMODEL))[threadIdx.x];
    v.x = bf2f(u.x); v.y = bf2f(u.y); v.z = bf2f(u.z); v.w = bf2f(u.w);
  }
  float s = v.x + v.y + v.z + v.w;
  float ss = fmaf(v.x, v.x, fmaf(v.y, v.y, fmaf(v.z, v.z, v.w * v.w)));
#pragma unroll
  for (int o = 32; o >= 1; o >>= 1) {
    s += __shfl_xor(s, o);
    ss += __shfl_xor(ss, o);
  }
  __shared__ float red[8];
  int w = threadIdx.x >> 6;
  if ((threadIdx.x & 63) == 0) { red[w] = s; red[4 + w] = ss; }
  __syncthreads();
  s = red[0] + red[1] + red[2] + red[3];
  ss = red[4] + red[5] + red[6] + red[7];
  float mu = s * (1.0f / DMODEL);
  float var = ss * (1.0f / DMODEL) - mu * mu;
  float rs = rsqrtf(var + LNEPS);
  float4 gg = ((const float4*)g)[threadIdx.x];
  float4 bb = ((const float4*)bta)[threadIdx.x];
  float4 o;
  o.x = (v.x - mu) * rs * gg.x + bb.x;
  o.y = (v.y - mu) * rs * gg.y + bb.y;
  o.z = (v.z - mu) * rs * gg.z + bb.z;
  o.w = (v.w - mu) * rs * gg.w + bb.w;
  if (Yf) ((float4*)(Yf + (size_t)row * DMODEL))[threadIdx.x] = o;
  if (Yb) {
    ushort4 ob;
    ob.x = f2bf(o.x); ob.y = f2bf(o.y); ob.z = f2bf(o.z); ob.w = f2bf(o.w);
    ((ushort4*)(Yb + (size_t)row * DMODEL))[threadIdx.x] = ob;
  }
}

// ---------------------------------------------------------------------------
extern "C" void kernel_launch(void* const* d_in, const int* in_sizes, int n_in,
                              void* d_out, int out_size, void* d_ws, size_t ws_size,
                              hipStream_t stream) {
  const int* tokens       = (const int*)d_in[0];
  const float* emb        = (const float*)d_in[1];
  const float* in_proj_w  = (const float*)d_in[2];
  const float* in_proj_b  = (const float*)d_in[3];
  const float* out_proj_w = (const float*)d_in[4];
  const float* out_proj_b = (const float*)d_in[5];
  const float* w1         = (const float*)d_in[6];
  const float* b1         = (const float*)d_in[7];
  const float* w2         = (const float*)d_in[8];
  const float* b2         = (const float*)d_in[9];
  const float* g1         = (const float*)d_in[10];
  const float* beta1      = (const float*)d_in[11];
  const float* g2         = (const float*)d_in[12];
  const float* beta2      = (const float*)d_in[13];
  float* out = (float*)d_out;

  char* ws = (char*)d_ws;
  const size_t MB = 1ull << 20;
  // Memory plan (peak 184 MiB), lifetimes:
  //   inwb [0,6) outwb [6,8) w1b [8,16) w2b [16,24)  bf16 weights (whole pass)
  //   y2b   [24,40)   bf16 ff2 out (live ff2..LN2)
  //   xb    [56,72)   bf16 embed out; residual for out-proj
  //   qkvb  [72,120)  bf16 qkv (live qkv-gemm..attn)
  //   hpre_b[72,88)   bf16 out-proj out (reuses qkvb, dead after attn)
  //   hb    [104,120) bf16 LN1 out (ff1 A + ff2 residual)
  //   vtb   [120,136) bf16 V^T (live vtrans..attn)
  //   ctxb  [136,152) bf16 attn out (live attn..out-proj)
  //   ffbb  [120,184) bf16 relu(ff1) (live ff1..ff2)
  unsigned short* inwb   = (unsigned short*)(ws + 0 * MB);
  unsigned short* outwb  = (unsigned short*)(ws + 6 * MB);
  unsigned short* w1b    = (unsigned short*)(ws + 8 * MB);
  unsigned short* w2b    = (unsigned short*)(ws + 16 * MB);
  unsigned short* y2b    = (unsigned short*)(ws + 24 * MB);
  unsigned short* xb     = (unsigned short*)(ws + 56 * MB);
  unsigned short* qkvb   = (unsigned short*)(ws + 72 * MB);
  unsigned short* hpre_b = (unsigned short*)(ws + 72 * MB);
  unsigned short* hb     = (unsigned short*)(ws + 104 * MB);
  unsigned short* vtb    = (unsigned short*)(ws + 120 * MB);
  unsigned short* ctxb   = (unsigned short*)(ws + 136 * MB);
  unsigned short* ffbb   = (unsigned short*)(ws + 120 * MB);

  const size_t GLDSP  = 131072;   // gemm8p: 128 KB
  const size_t GLDSPN = 98304;    // gemm8p128: 96 KB

  // 1. fused embed(+posenc) -> xb and weight cvt (one launch)
  prep_kernel<<<28672, 256, 0, stream>>>(tokens, emb, xb,
                                         in_proj_w, out_proj_w, w1, w2,
                                         inwb, outwb, w1b, w2b);
  // 2. qkv = x @ in_proj_w^T + b  (bf16 out)  [768 blocks = 3 exact CU-waves]
  gemm8p128<<<(MROWS / 256) * (3 * DMODEL / 128), 512, GLDSPN, stream>>>(
      xb, inwb, in_proj_b, nullptr, nullptr, nullptr, qkvb, MROWS, 3 * DMODEL, DMODEL, 0);
  // 3. V^T pre-transpose
  vtrans_kernel<<<dim3(SEQ / 64, BATCH * NH), 256, 0, stream>>>(qkvb, vtb);
  // 4. flash attention v5 -> ctxb (bf16)   [512 blocks]
  attn_kernel<<<(SEQ / 256) * (BATCH * NH), 512, 0, stream>>>(qkvb, vtb, ctxb);
  // 5. hpre = ctx @ out_proj_w^T + b + xb  (bf16 out)   [256 blocks]
  gemm8p128<<<(MROWS / 256) * (DMODEL / 128), 512, GLDSPN, stream>>>(
      ctxb, outwb, out_proj_b, nullptr, xb, nullptr, hpre_b, MROWS, DMODEL, DMODEL, 0);
  // 6. hb = LN1(hpre)  (bf16 in, bf16 out)
  ln_kernel<<<MROWS, 256, 0, stream>>>(nullptr, hpre_b, g1, beta1, nullptr, hb);
  // 7. ffb = relu(hb @ w1^T + b1)  (bf16 out)   [512 blocks, 8-phase 256x256]
  gemm8p<<<(MROWS / 256) * (DFF / 256), 512, GLDSP, stream>>>(
      hb, w1b, b1, nullptr, nullptr, ffbb, MROWS, DFF, DMODEL, 1);
  // 8. y2b = ffb @ w2^T + b2 + hb  (bf16 out)   [256 blocks]
  gemm8p128<<<(MROWS / 256) * (DMODEL / 128), 512, GLDSPN, stream>>>(
      ffbb, w2b, b2, nullptr, hb, nullptr, y2b, MROWS, DMODEL, DFF, 0);
  // 9. out = LN2(y2b)  (bf16 in, f32 out)
  ln_kernel<<<MROWS, 256, 0, stream>>>(nullptr, y2b, g2, beta2, out, nullptr);
}

// Round 15
// 378.095 us; speedup vs baseline: 1.0784x; 1.0189x over previous
//
#include <hip/hip_runtime.h>
#include <math.h>

#define DMODEL 1024
#define NH 16
#define DHEAD 64
#define DFF 4096
#define BATCH 4
#define SEQ 2048
#define MROWS (BATCH * SEQ)   // 8192
#define LNEPS 1e-5f
#define NT (SEQ / 64)         // 32 kv tiles

typedef __attribute__((ext_vector_type(8))) short bf16x8;
typedef __attribute__((ext_vector_type(4))) float f32x4;
typedef __attribute__((ext_vector_type(16))) float f32x16;
typedef __attribute__((ext_vector_type(4))) unsigned int u32x4;

__device__ inline unsigned short f2bf(float f) {
  unsigned int u = __float_as_uint(f);
  unsigned int r = (u + 0x7fffu + ((u >> 16) & 1u)) >> 16;  // RNE
  return (unsigned short)r;
}
__device__ inline float bf2f(unsigned short b) {
  return __uint_as_float(((unsigned int)b) << 16);
}

__device__ inline void gload16(const unsigned short* g, char* l) {
  __builtin_amdgcn_global_load_lds(
      (const __attribute__((address_space(1))) unsigned int*)g,
      (__attribute__((address_space(3))) unsigned int*)l, 16, 0, 0);
}

__device__ inline float fexp2(float x) {
  float r;
  asm("v_exp_f32 %0, %1" : "=v"(r) : "v"(x));
  return r;
}
__device__ inline unsigned int cvtpk(float lo, float hi) {
  unsigned int r;
  asm("v_cvt_pk_bf16_f32 %0, %1, %2" : "=v"(r) : "v"(lo), "v"(hi));
  return r;
}
__device__ inline void plswap(unsigned int& a, unsigned int& b) {
  asm("v_permlane32_swap_b32 %0, %1" : "+v"(a), "+v"(b));
}

// ---------------------------------------------------------------------------
// Fused prologue: blocks [0,16384) do embedding+pos-enc -> bf16 xb;
// blocks [16384, 28672) do the 4-weight fp32->bf16 conversion.
// ---------------------------------------------------------------------------
__global__ __launch_bounds__(256)
void prep_kernel(const int* __restrict__ tokens, const float* __restrict__ emb,
                 unsigned short* __restrict__ Xb,
                 const float* __restrict__ a, const float* __restrict__ b,
                 const float* __restrict__ c, const float* __restrict__ d,
                 unsigned short* __restrict__ oa, unsigned short* __restrict__ ob,
                 unsigned short* __restrict__ oc, unsigned short* __restrict__ od) {
  const int bid = blockIdx.x;
  if (bid < 16384) {
    const int HALF = DMODEL / 2;
    int idx = bid * 256 + threadIdx.x;
    int row = idx / HALF;
    int j = idx - row * HALF;
    int s = row & (SEQ - 1);
    int tok = tokens[row];
    float2 e = ((const float2*)(emb + (size_t)tok * DMODEL))[j];
    float denom = powf(10000.0f, (2.0f * (float)(2 * j)) / (float)DMODEL);
    float ang = (float)s / denom;
    float sn, cs;
    sincosf(ang, &sn, &cs);
    ushort2 o2;
    o2.x = f2bf(e.x + sn);
    o2.y = f2bf(e.y + cs);
    ((ushort2*)(Xb + (size_t)row * DMODEL))[j] = o2;
  } else {
    int i = (bid - 16384) * 256 + threadIdx.x;
    const float* src; unsigned short* dst; int off;
    if (i < 786432)       { src = a; dst = oa; off = 0; }
    else if (i < 1048576) { src = b; dst = ob; off = 786432; }
    else if (i < 2097152) { src = c; dst = oc; off = 1048576; }
    else                  { src = d; dst = od; off = 2097152; }
    int j = i - off;
    float4 v = ((const float4*)src)[j];
    ushort4 o;
    o.x = f2bf(v.x); o.y = f2bf(v.y); o.z = f2bf(v.z); o.w = f2bf(v.w);
    ((ushort4*)dst)[j] = o;
  }
}

// ---------------------------------------------------------------------------
// gemm8p: 8-phase 256x256 GEMM (round-10 structure; ff1 only).
// ---------------------------------------------------------------------------
__device__ inline void sthalf8(const unsigned short* G, int grow0, int K, int kt,
                               char* smem_, int isB, int half, int t) {
  char* dst = smem_ + ((kt & 1) * 65536) + isB * 32768 + half * 16384;
#pragma unroll
  for (int i = 0; i < 2; ++i) {
    int g = i * 512 + t;
    int r = g >> 3, sl = g & 7;
    int c = sl ^ (r & 7);
    gload16(G + (size_t)(grow0 + half * 128 + r) * K + kt * 64 + c * 8, dst + g * 16);
  }
}

#define VM4_ asm volatile("s_waitcnt vmcnt(4)" ::: "memory")
#define VM2_ asm volatile("s_waitcnt vmcnt(2)" ::: "memory")
#define VM0_ asm volatile("s_waitcnt vmcnt(0)" ::: "memory")

#define PHASE8(bufofs, MG, NP, LA, LB, STAGE_STMT, WAIT_STMT)                   \
  {                                                                             \
    if (LA) {                                                                   \
      _Pragma("unroll") for (int m = 0; m < 4; ++m) {                           \
        int arow = wm * 128 + (MG) * 64 + m * 16 + fr;                          \
        _Pragma("unroll") for (int ks = 0; ks < 2; ++ks)                        \
          af[m][ks] = *(const bf16x8*)(smem + (bufofs) + arow * 128 +           \
                        (((ks * 4 + fq) ^ (arow & 7)) * 16));                   \
      }                                                                         \
    }                                                                           \
    if (LB) {                                                                   \
      _Pragma("unroll") for (int nn = 0; nn < 2; ++nn) {                        \
        int n = (NP) * 2 + nn;                                                  \
        int brow = wn * 64 + n * 16 + fr;                                       \
        _Pragma("unroll") for (int ks = 0; ks < 2; ++ks)                        \
          bf[(NP) * 2 + nn][ks] = *(const bf16x8*)(smem + (bufofs) + 32768 +    \
                        brow * 128 + (((ks * 4 + fq) ^ (brow & 7)) * 16));      \
      }                                                                         \
    }                                                                           \
    STAGE_STMT;                                                                 \
    __builtin_amdgcn_sched_barrier(0);                                          \
    __builtin_amdgcn_s_barrier();                                               \
    asm volatile("s_waitcnt lgkmcnt(0)" ::: "memory");                          \
    __builtin_amdgcn_sched_barrier(0);                                          \
    __builtin_amdgcn_s_setprio(1);                                              \
    _Pragma("unroll") for (int m = 0; m < 4; ++m)                               \
      _Pragma("unroll") for (int nn = 0; nn < 2; ++nn)                          \
        _Pragma("unroll") for (int ks = 0; ks < 2; ++ks)                        \
          acc[(MG) * 4 + m][(NP) * 2 + nn] =                                    \
              __builtin_amdgcn_mfma_f32_16x16x32_bf16(                          \
                  af[m][ks], bf[(NP) * 2 + nn][ks],                             \
                  acc[(MG) * 4 + m][(NP) * 2 + nn], 0, 0, 0);                   \
    __builtin_amdgcn_s_setprio(0);                                              \
    WAIT_STMT;                                                                  \
    __builtin_amdgcn_sched_barrier(0);                                          \
    __builtin_amdgcn_s_barrier();                                               \
    __builtin_amdgcn_sched_barrier(0);                                          \
  }

__global__ __launch_bounds__(512, 2)
void gemm8p(const unsigned short* __restrict__ A, const unsigned short* __restrict__ B,
            const float* __restrict__ bias, const float* __restrict__ resid,
            float* __restrict__ Cf, unsigned short* __restrict__ Cb,
            int M, int N, int K, int relu) {
  extern __shared__ char smem[];   // 131072: 2 bufs x (A 32K + B 32K)

  const int t = threadIdx.x;
  const int lane = t & 63;
  const int wv = t >> 6;
  const int wm = wv >> 2;
  const int wn = wv & 3;
  const int fr = lane & 15;
  const int fq = lane >> 4;

  const int nwg = gridDim.x;
  const int orig = blockIdx.x;
  const int q8 = nwg >> 3;
  const int wgid = (orig & 7) * q8 + (orig >> 3);
  const int stid = wgid >> 2, within = wgid & 3;
  const int sm = within & 1, sn = within >> 1;
  const int Msup = M >> 9;
  const int stm = stid % Msup, stn = stid / Msup;
  const int m0 = (stm * 2 + sm) * 256;
  const int n0 = (stn * 2 + sn) * 256;

  f32x4 acc[8][4];
#pragma unroll
  for (int m = 0; m < 8; ++m)
#pragma unroll
    for (int n = 0; n < 4; ++n) acc[m][n] = (f32x4){0.f, 0.f, 0.f, 0.f};

  const int nk = K / 64;
  const int nj = nk / 2;

  sthalf8(A, m0, K, 0, smem, 0, 0, t);
  sthalf8(A, m0, K, 0, smem, 0, 1, t);
  sthalf8(B, n0, K, 0, smem, 1, 0, t);
  sthalf8(B, n0, K, 0, smem, 1, 1, t);
  sthalf8(B, n0, K, 1, smem, 1, 0, t);
  sthalf8(B, n0, K, 1, smem, 1, 1, t);
  VM4_;
  __builtin_amdgcn_sched_barrier(0);
  __builtin_amdgcn_s_barrier();
  __builtin_amdgcn_sched_barrier(0);

  bf16x8 af[4][2];
  bf16x8 bf[4][2];

  for (int j = 0; j < nj; ++j) {
    const bool st = (j + 1 < nj);
    PHASE8(0, 0, 0, 1, 1, sthalf8(A, m0, K, 2 * j + 1, smem, 0, 0, t), );
    PHASE8(0, 0, 1, 0, 1, sthalf8(A, m0, K, 2 * j + 1, smem, 0, 1, t), );
    PHASE8(0, 1, 1, 1, 0,
           if (st) sthalf8(B, n0, K, 2 * j + 2, smem, 1, 0, t), );
    PHASE8(0, 1, 0, 0, 0,
           if (st) sthalf8(B, n0, K, 2 * j + 2, smem, 1, 1, t),
           { if (st) { VM4_; } else { VM0_; } });
    PHASE8(65536, 0, 0, 1, 1,
           if (st) sthalf8(A, m0, K, 2 * j + 2, smem, 0, 0, t), );
    PHASE8(65536, 0, 1, 0, 1,
           if (st) sthalf8(A, m0, K, 2 * j + 2, smem, 0, 1, t), );
    PHASE8(65536, 1, 1, 1, 0,
           if (st) sthalf8(B, n0, K, 2 * j + 3, smem, 1, 0, t), );
    PHASE8(65536, 1, 0, 0, 0,
           if (st) sthalf8(B, n0, K, 2 * j + 3, smem, 1, 1, t),
           { if (st) { VM4_; } });
  }

  float* slab = (float*)(smem + wv * 4352);
#pragma unroll
  for (int m = 0; m < 8; ++m) {
#pragma unroll
    for (int n = 0; n < 4; ++n)
#pragma unroll
      for (int j = 0; j < 4; ++j)
        slab[(fq * 4 + j) * 68 + n * 16 + fr] = acc[m][n][j];
    int rg0 = m0 + wm * 128 + m * 16;
#pragma unroll
    for (int it = 0; it < 4; ++it) {
      int u = it * 64 + lane;
      int row = u >> 4, seg = u & 15;
      float4 v = *(const float4*)&slab[row * 68 + seg * 4];
      int col = n0 + wn * 64 + seg * 4;
      float4 b4 = *(const float4*)&bias[col];
      v.x += b4.x; v.y += b4.y; v.z += b4.z; v.w += b4.w;
      if (relu) {
        v.x = fmaxf(v.x, 0.f); v.y = fmaxf(v.y, 0.f);
        v.z = fmaxf(v.z, 0.f); v.w = fmaxf(v.w, 0.f);
      }
      size_t idx = (size_t)(rg0 + row) * N + col;
      if (resid) {
        float4 r4 = *(const float4*)&resid[idx];
        v.x += r4.x; v.y += r4.y; v.z += r4.z; v.w += r4.w;
      }
      if (Cf) {
        *(float4*)&Cf[idx] = v;
      } else {
        ushort4 ob;
        ob.x = f2bf(v.x); ob.y = f2bf(v.y); ob.z = f2bf(v.z); ob.w = f2bf(v.w);
        *(ushort4*)&Cb[idx] = ob;
      }
    }
  }
}

// ---------------------------------------------------------------------------
// gemm8p128: fine-phase schedule at BM=256, BN=128 (qkv, out-proj, ff2).
// Residual f32 (resid) or bf16 (residb); output f32 (Cf) or bf16 (Cb).
// vtb mode (qkv only): waves whose 64-col range is >= col 2048 (the V part)
// write their slab TRANSPOSED to vtb[(bh*64+d)*SEQ + s] (bit-identical RNE
// via v_cvt_pk) and skip the Cb write — folds the V^T pass into this kernel.
// ---------------------------------------------------------------------------
__device__ inline void stA128(const unsigned short* G, int m0, int K, int kt,
                              int half, char* smem_, int t) {
  char* dst = smem_ + ((kt & 1) * 49152) + half * 16384;
#pragma unroll
  for (int i = 0; i < 2; ++i) {
    int g = i * 512 + t;
    int r = g >> 3, sl = g & 7;
    int c = sl ^ (r & 7);
    gload16(G + (size_t)(m0 + half * 128 + r) * K + kt * 64 + c * 8, dst + g * 16);
  }
}
__device__ inline void stB128(const unsigned short* G, int n0, int K, int kt,
                              char* smem_, int t) {
  char* dst = smem_ + ((kt & 1) * 49152) + 32768;
#pragma unroll
  for (int i = 0; i < 2; ++i) {
    int g = i * 512 + t;
    int r = g >> 3, sl = g & 7;
    int c = sl ^ (r & 7);
    gload16(G + (size_t)(n0 + r) * K + kt * 64 + c * 8, dst + g * 16);
  }
}

#define PH128(bufofs, MG, NP, LA, LB, STAGE_STMT, WAIT_STMT)                    \
  {                                                                             \
    if (LA) {                                                                   \
      _Pragma("unroll") for (int mm = 0; mm < 2; ++mm) {                        \
        int arow = wm * 64 + ((MG) * 2 + mm) * 16 + fr;                         \
        _Pragma("unroll") for (int ks = 0; ks < 2; ++ks)                        \
          af[mm][ks] = *(const bf16x8*)(smem + (bufofs) + arow * 128 +          \
                        (((ks * 4 + fq) ^ (arow & 7)) * 16));                   \
      }                                                                         \
    }                                                                           \
    if (LB) {                                                                   \
      _Pragma("unroll") for (int nn = 0; nn < 2; ++nn) {                        \
        int n = (NP) * 2 + nn;                                                  \
        int brow = wn * 64 + n * 16 + fr;                                       \
        _Pragma("unroll") for (int ks = 0; ks < 2; ++ks)                        \
          bf[(NP) * 2 + nn][ks] = *(const bf16x8*)(smem + (bufofs) + 32768 +    \
                        brow * 128 + (((ks * 4 + fq) ^ (brow & 7)) * 16));      \
      }                                                                         \
    }                                                                           \
    STAGE_STMT;                                                                 \
    __builtin_amdgcn_sched_barrier(0);                                          \
    __builtin_amdgcn_s_barrier();                                               \
    asm volatile("s_waitcnt lgkmcnt(0)" ::: "memory");                          \
    __builtin_amdgcn_sched_barrier(0);                                          \
    __builtin_amdgcn_s_setprio(1);                                              \
    _Pragma("unroll") for (int mm = 0; mm < 2; ++mm)                            \
      _Pragma("unroll") for (int nn = 0; nn < 2; ++nn)                          \
        _Pragma("unroll") for (int ks = 0; ks < 2; ++ks)                        \
          acc[(MG) * 2 + mm][(NP) * 2 + nn] =                                   \
              __builtin_amdgcn_mfma_f32_16x16x32_bf16(                          \
                  af[mm][ks], bf[(NP) * 2 + nn][ks],                            \
                  acc[(MG) * 2 + mm][(NP) * 2 + nn], 0, 0, 0);                  \
    __builtin_amdgcn_s_setprio(0);                                              \
    WAIT_STMT;                                                                  \
    __builtin_amdgcn_sched_barrier(0);                                          \
    __builtin_amdgcn_s_barrier();                                               \
    __builtin_amdgcn_sched_barrier(0);                                          \
  }

__global__ __launch_bounds__(512, 2)
void gemm8p128(const unsigned short* __restrict__ A, const unsigned short* __restrict__ B,
               const float* __restrict__ bias, const float* __restrict__ resid,
               const unsigned short* __restrict__ residb,
               float* __restrict__ Cf, unsigned short* __restrict__ Cb,
               unsigned short* __restrict__ vtb,
               int M, int N, int K, int relu) {
  extern __shared__ char smem[];   // 98304: 2 bufs x (A 32K + B 16K)

  const int t = threadIdx.x;
  const int lane = t & 63;
  const int wv = t >> 6;
  const int wm = wv >> 1;
  const int wn = wv & 1;
  const int fr = lane & 15;
  const int fq = lane >> 4;

  const int nwg = gridDim.x;
  const int orig = blockIdx.x;
  const int q8 = nwg >> 3;
  const int wgid = (orig & 7) * q8 + (orig >> 3);
  const int stid = wgid >> 2, within = wgid & 3;
  const int sm = within & 1, sn = within >> 1;
  const int Msup = M >> 9;
  const int stm = stid % Msup, stn = stid / Msup;
  const int m0 = (stm * 2 + sm) * 256;
  const int n0 = (stn * 2 + sn) * 128;

  f32x4 acc[4][4];
#pragma unroll
  for (int m = 0; m < 4; ++m)
#pragma unroll
    for (int n = 0; n < 4; ++n) acc[m][n] = (f32x4){0.f, 0.f, 0.f, 0.f};

  const int nk = K / 64;
  const int nj = nk / 2;

  stA128(A, m0, K, 0, 0, smem, t);
  stA128(A, m0, K, 0, 1, smem, t);
  stB128(B, n0, K, 0, smem, t);
  stB128(B, n0, K, 1, smem, t);
  VM2_;
  __builtin_amdgcn_sched_barrier(0);
  __builtin_amdgcn_s_barrier();
  __builtin_amdgcn_sched_barrier(0);

  bf16x8 af[2][2];
  bf16x8 bf[4][2];

  for (int j = 0; j < nj; ++j) {
    const bool st = (j + 1 < nj);
    const int k1 = 2 * j + 1;
    PH128(0, 0, 0, 1, 1, stA128(A, m0, K, k1, 0, smem, t), );
    PH128(0, 0, 1, 0, 1, stA128(A, m0, K, k1, 1, smem, t), );
    PH128(0, 1, 0, 1, 0,
          if (st) stB128(B, n0, K, k1 + 1, smem, t), );
    PH128(0, 1, 1, 0, 0,
          if (st) stA128(A, m0, K, k1 + 1, 0, smem, t),
          { if (st) { VM4_; } else { VM0_; } });
    PH128(49152, 0, 0, 1, 1,
          if (st) stA128(A, m0, K, k1 + 1, 1, smem, t), );
    PH128(49152, 0, 1, 0, 1, , );
    PH128(49152, 1, 0, 1, 0,
          if (st) stB128(B, n0, K, k1 + 2, smem, t), );
    PH128(49152, 1, 1, 0, 0, ,
          { if (st) { VM2_; } });
  }

  float* slab = (float*)(smem + wv * 4352);
  const bool vmode = (vtb != nullptr) && ((n0 + wn * 64) >= 2 * DMODEL);
  if (vmode) {
    // transposed V write: lane owns col d; 16 s-values packed per m-subtile
    int vcol = n0 + wn * 64 + lane - 2 * DMODEL;
    int h = vcol >> 6, d = vcol & 63;
    int b = m0 >> 11;                         // m0 / SEQ
    unsigned short* vdst = vtb + ((size_t)(b * NH + h) * 64 + d) * SEQ;
    float bv = bias[n0 + wn * 64 + lane];
#pragma unroll
    for (int m = 0; m < 4; ++m) {
#pragma unroll
      for (int n = 0; n < 4; ++n)
#pragma unroll
        for (int j = 0; j < 4; ++j)
          slab[(fq * 4 + j) * 68 + n * 16 + fr] = acc[m][n][j];
      int s0 = (m0 & (SEQ - 1)) + wm * 64 + m * 16;
      unsigned int pk[8];
#pragma unroll
      for (int r2 = 0; r2 < 8; ++r2)
        pk[r2] = cvtpk(slab[(2 * r2) * 68 + lane] + bv,
                       slab[(2 * r2 + 1) * 68 + lane] + bv);
      *(uint4*)(vdst + s0) = *(uint4*)&pk[0];
      *(uint4*)(vdst + s0 + 8) = *(uint4*)&pk[4];
    }
  } else {
#pragma unroll
    for (int m = 0; m < 4; ++m) {
#pragma unroll
      for (int n = 0; n < 4; ++n)
#pragma unroll
        for (int j = 0; j < 4; ++j)
          slab[(fq * 4 + j) * 68 + n * 16 + fr] = acc[m][n][j];
      int rg0 = m0 + wm * 64 + m * 16;
#pragma unroll
      for (int it = 0; it < 4; ++it) {
        int u = it * 64 + lane;
        int row = u >> 4, seg = u & 15;
        float4 v = *(const float4*)&slab[row * 68 + seg * 4];
        int col = n0 + wn * 64 + seg * 4;
        float4 b4 = *(const float4*)&bias[col];
        v.x += b4.x; v.y += b4.y; v.z += b4.z; v.w += b4.w;
        if (relu) {
          v.x = fmaxf(v.x, 0.f); v.y = fmaxf(v.y, 0.f);
          v.z = fmaxf(v.z, 0.f); v.w = fmaxf(v.w, 0.f);
        }
        size_t idx = (size_t)(rg0 + row) * N + col;
        if (resid) {
          float4 r4 = *(const float4*)&resid[idx];
          v.x += r4.x; v.y += r4.y; v.z += r4.z; v.w += r4.w;
        } else if (residb) {
          ushort4 r4 = *(const ushort4*)&residb[idx];
          v.x += bf2f(r4.x); v.y += bf2f(r4.y); v.z += bf2f(r4.z); v.w += bf2f(r4.w);
        }
        if (Cf) {
          *(float4*)&Cf[idx] = v;
        } else {
          ushort4 ob;
          ob.x = f2bf(v.x); ob.y = f2bf(v.y); ob.z = f2bf(v.z); ob.w = f2bf(v.w);
          *(ushort4*)&Cb[idx] = ob;
        }
      }
    }
  }
}

// ---------------------------------------------------------------------------
// MFMA flash attention v5 (round-9 structure, best measured).
// ---------------------------------------------------------------------------
__global__ __launch_bounds__(512, 4)
void attn_kernel(const unsigned short* __restrict__ qkv, const unsigned short* __restrict__ vtb,
                 unsigned short* __restrict__ ctxb) {
  __shared__ __align__(16) unsigned short Ks[2][64][64];
  __shared__ __align__(16) unsigned short Vts[2][64][64];
  __shared__ __align__(16) unsigned short Slab[8][32][64];

  const int t = threadIdx.x;
  const int lane = t & 63;
  const int wq = t >> 6;
  const int l31 = lane & 31;
  const int hi1 = lane >> 5;
  const int bid = blockIdx.x;
  const int bh = bid & 63;
  const int qt = bid >> 6;
  const int b = bh >> 4, h = bh & 15;
  const int q0 = qt * 256;

  const size_t RS = 3 * DMODEL;
  const unsigned short* qb = qkv + (size_t)b * SEQ * RS + h * DHEAD;
  const unsigned short* kb = qb + DMODEL;

  bf16x8 qf[4];
  {
    const unsigned short* qrow = qb + (size_t)(q0 + wq * 32 + l31) * RS;
#pragma unroll
    for (int s = 0; s < 4; ++s)
      qf[s] = *(const bf16x8*)(qrow + s * 16 + hi1 * 8);
  }

  const unsigned short* kgl =
      kb + (size_t)(wq * 8 + (lane >> 3)) * RS + ((lane & 7) ^ (lane >> 3)) * 8;
  const unsigned short* vgl =
      vtb + ((size_t)bh * 64 + wq * 8 + (lane >> 3)) * SEQ + ((lane & 7) ^ (lane >> 3)) * 8;

  f32x16 oacc[2] = {};
  float lacc = 0.f;

  gload16(kgl, (char*)&Ks[0][wq * 8][0]);
  gload16(vgl, (char*)&Vts[0][wq * 8][0]);
  __syncthreads();

  const float C = 0.18033688011112042f;   // 0.125 * log2(e)

  for (int kt = 0; kt < NT; ++kt) {
    const int cur = kt & 1;
    if (kt + 1 < NT) {
      gload16(kgl + (size_t)(kt + 1) * 64 * RS, (char*)&Ks[cur ^ 1][wq * 8][0]);
      gload16(vgl + (size_t)(kt + 1) * 64, (char*)&Vts[cur ^ 1][wq * 8][0]);
    }

    f32x16 sacc[2] = {};
    __builtin_amdgcn_s_setprio(1);
#pragma unroll
    for (int s = 0; s < 4; ++s) {
#pragma unroll
      for (int kvt = 0; kvt < 2; ++kvt) {
        int row = kvt * 32 + l31;
        bf16x8 kf = *(const bf16x8*)&Ks[cur][row][(((2 * s + hi1) ^ (row & 7)) * 8)];
        sacc[kvt] = __builtin_amdgcn_mfma_f32_32x32x16_bf16(kf, qf[s], sacc[kvt], 0, 0, 0);
      }
    }
    __builtin_amdgcn_s_setprio(0);

#pragma unroll
    for (int kvt = 0; kvt < 2; ++kvt) {
      float p[16];
#pragma unroll
      for (int r = 0; r < 16; ++r) p[r] = fexp2(sacc[kvt][r] * C);
      float ps = 0.f;
#pragma unroll
      for (int r = 0; r < 16; ++r) ps += p[r];
      lacc += ps;
#pragma unroll
      for (int half = 0; half < 2; ++half) {
        const int lo = half * 8;
        unsigned int x0 = cvtpk(p[lo + 0], p[lo + 1]);
        unsigned int x1 = cvtpk(p[lo + 2], p[lo + 3]);
        unsigned int y0 = cvtpk(p[lo + 4], p[lo + 5]);
        unsigned int y1 = cvtpk(p[lo + 6], p[lo + 7]);
        plswap(x0, y0);
        plswap(x1, y1);
        bf16x8 pa = __builtin_bit_cast(bf16x8, (u32x4){x0, x1, y0, y1});
        const int s2 = kvt * 2 + half;
        __builtin_amdgcn_s_setprio(1);
#pragma unroll
        for (int dt = 0; dt < 2; ++dt) {
          int vrow = dt * 32 + l31;
          bf16x8 vf = *(const bf16x8*)&Vts[cur][vrow][(((2 * s2 + hi1) ^ (vrow & 7)) * 8)];
          oacc[dt] = __builtin_amdgcn_mfma_f32_32x32x16_bf16(pa, vf, oacc[dt], 0, 0, 0);
        }
        __builtin_amdgcn_s_setprio(0);
      }
    }
    __syncthreads();
  }

  lacc += __shfl_xor(lacc, 32);
  float inv = 1.0f / lacc;

  float iv[16];
#pragma unroll
  for (int r = 0; r < 16; ++r)
    iv[r] = __shfl(inv, (r & 3) + 8 * (r >> 2) + 4 * hi1);

#pragma unroll
  for (int dt = 0; dt < 2; ++dt) {
    const int chunk = dt * 4 + (l31 >> 3);
    const int e7 = l31 & 7;
#pragma unroll
    for (int r = 0; r < 16; ++r) {
      int qp = (r & 3) + 8 * (r >> 2) + 4 * hi1;
      Slab[wq][qp][((chunk ^ (qp & 7)) * 8) + e7] = f2bf(oacc[dt][r] * iv[r]);
    }
  }
#pragma unroll
  for (int it = 0; it < 4; ++it) {
    int u = it * 64 + lane;
    int row = u >> 3, s = u & 7;
    uint4 v = *(const uint4*)&Slab[wq][row][((s ^ (row & 7)) * 8)];
    *(uint4*)(ctxb + (size_t)(b * SEQ + q0 + wq * 32 + row) * DMODEL + h * DHEAD + s * 8) = v;
  }
}

// ---------------------------------------------------------------------------
// LayerNorm: input f32 (Zf) or bf16 (Zb); outputs f32 (Yf) and/or bf16 (Yb).
// ---------------------------------------------------------------------------
__global__ __launch_bounds__(256)
void ln_kernel(const float* __restrict__ Zf, const unsigned short* __restrict__ Zb,
               const float* __restrict__ g, const float* __restrict__ bta,
               float* __restrict__ Yf, unsigned short* __restrict__ Yb) {
  const int row = blockIdx.x;
  float4 v;
  if (Zf) {
    v = ((const float4*)(Zf + (size_t)row * DMODEL))[threadIdx.x];
  } else {
    ushort4 u = ((const ushort4*)(Zb + (size_t)row * DMODEL))[threadIdx.x];
    v.x = bf2f(u.x); v.y = bf2f(u.y); v.z = bf2f(u.z); v.w = bf2f(u.w);
  }
  float s = v.x + v.y + v.z + v.w;
  float ss = fmaf(v.x, v.x, fmaf(v.y, v.y, fmaf(v.z, v.z, v.w * v.w)));
#pragma unroll
  for (int o = 32; o >= 1; o >>= 1) {
    s += __shfl_xor(s, o);
    ss += __shfl_xor(ss, o);
  }
  __shared__ float red[8];
  int w = threadIdx.x >> 6;
  if ((threadIdx.x & 63) == 0) { red[w] = s; red[4 + w] = ss; }
  __syncthreads();
  s = red[0] + red[1] + red[2] + red[3];
  ss = red[4] + red[5] + red[6] + red[7];
  float mu = s * (1.0f / DMODEL);
  float var = ss * (1.0f / DMODEL) - mu * mu;
  float rs = rsqrtf(var + LNEPS);
  float4 gg = ((const float4*)g)[threadIdx.x];
  float4 bb = ((const float4*)bta)[threadIdx.x];
  float4 o;
  o.x = (v.x - mu) * rs * gg.x + bb.x;
  o.y = (v.y - mu) * rs * gg.y + bb.y;
  o.z = (v.z - mu) * rs * gg.z + bb.z;
  o.w = (v.w - mu) * rs * gg.w + bb.w;
  if (Yf) ((float4*)(Yf + (size_t)row * DMODEL))[threadIdx.x] = o;
  if (Yb) {
    ushort4 ob;
    ob.x = f2bf(o.x); ob.y = f2bf(o.y); ob.z = f2bf(o.z); ob.w = f2bf(o.w);
    ((ushort4*)(Yb + (size_t)row * DMODEL))[threadIdx.x] = ob;
  }
}

// ---------------------------------------------------------------------------
extern "C" void kernel_launch(void* const* d_in, const int* in_sizes, int n_in,
                              void* d_out, int out_size, void* d_ws, size_t ws_size,
                              hipStream_t stream) {
  const int* tokens       = (const int*)d_in[0];
  const float* emb        = (const float*)d_in[1];
  const float* in_proj_w  = (const float*)d_in[2];
  const float* in_proj_b  = (const float*)d_in[3];
  const float* out_proj_w = (const float*)d_in[4];
  const float* out_proj_b = (const float*)d_in[5];
  const float* w1         = (const float*)d_in[6];
  const float* b1         = (const float*)d_in[7];
  const float* w2         = (const float*)d_in[8];
  const float* b2         = (const float*)d_in[9];
  const float* g1         = (const float*)d_in[10];
  const float* beta1      = (const float*)d_in[11];
  const float* g2         = (const float*)d_in[12];
  const float* beta2      = (const float*)d_in[13];
  float* out = (float*)d_out;

  char* ws = (char*)d_ws;
  const size_t MB = 1ull << 20;
  // Memory plan (peak 184 MiB), lifetimes:
  //   inwb [0,6) outwb [6,8) w1b [8,16) w2b [16,24)  bf16 weights (whole pass)
  //   y2b   [24,40)   bf16 ff2 out (live ff2..LN2)
  //   xb    [56,72)   bf16 embed out; residual for out-proj
  //   qkvb  [72,120)  bf16 Q,K (V region unwritten; live qkv..attn)
  //   hpre_b[72,88)   bf16 out-proj out (reuses qkvb, dead after attn)
  //   hb    [104,120) bf16 LN1 out (ff1 A + ff2 residual)
  //   vtb   [120,136) bf16 V^T (written by qkv epilogue; live ..attn)
  //   ctxb  [136,152) bf16 attn out (live attn..out-proj)
  //   ffbb  [120,184) bf16 relu(ff1) (live ff1..ff2)
  unsigned short* inwb   = (unsigned short*)(ws + 0 * MB);
  unsigned short* outwb  = (unsigned short*)(ws + 6 * MB);
  unsigned short* w1b    = (unsigned short*)(ws + 8 * MB);
  unsigned short* w2b    = (unsigned short*)(ws + 16 * MB);
  unsigned short* y2b    = (unsigned short*)(ws + 24 * MB);
  unsigned short* xb     = (unsigned short*)(ws + 56 * MB);
  unsigned short* qkvb   = (unsigned short*)(ws + 72 * MB);
  unsigned short* hpre_b = (unsigned short*)(ws + 72 * MB);
  unsigned short* hb     = (unsigned short*)(ws + 104 * MB);
  unsigned short* vtb    = (unsigned short*)(ws + 120 * MB);
  unsigned short* ctxb   = (unsigned short*)(ws + 136 * MB);
  unsigned short* ffbb   = (unsigned short*)(ws + 120 * MB);

  const size_t GLDSP  = 131072;   // gemm8p: 128 KB
  const size_t GLDSPN = 98304;    // gemm8p128: 96 KB

  // 1. fused embed(+posenc) -> xb and weight cvt (one launch)
  prep_kernel<<<28672, 256, 0, stream>>>(tokens, emb, xb,
                                         in_proj_w, out_proj_w, w1, w2,
                                         inwb, outwb, w1b, w2b);
  // 2. qkv = x @ in_proj_w^T + b; Q,K -> qkvb, V -> vtb (transposed epilogue)
  gemm8p128<<<(MROWS / 256) * (3 * DMODEL / 128), 512, GLDSPN, stream>>>(
      xb, inwb, in_proj_b, nullptr, nullptr, nullptr, qkvb, vtb,
      MROWS, 3 * DMODEL, DMODEL, 0);
  // 3. flash attention v5 -> ctxb (bf16)   [512 blocks]
  attn_kernel<<<(SEQ / 256) * (BATCH * NH), 512, 0, stream>>>(qkvb, vtb, ctxb);
  // 4. hpre = ctx @ out_proj_w^T + b + xb  (bf16 out)   [256 blocks]
  gemm8p128<<<(MROWS / 256) * (DMODEL / 128), 512, GLDSPN, stream>>>(
      ctxb, outwb, out_proj_b, nullptr, xb, nullptr, hpre_b, nullptr,
      MROWS, DMODEL, DMODEL, 0);
  // 5. hb = LN1(hpre)  (bf16 in, bf16 out)
  ln_kernel<<<MROWS, 256, 0, stream>>>(nullptr, hpre_b, g1, beta1, nullptr, hb);
  // 6. ffb = relu(hb @ w1^T + b1)  (bf16 out)   [512 blocks, 8-phase 256x256]
  gemm8p<<<(MROWS / 256) * (DFF / 256), 512, GLDSP, stream>>>(
      hb, w1b, b1, nullptr, nullptr, ffbb, MROWS, DFF, DMODEL, 1);
  // 7. y2b = ffb @ w2^T + b2 + hb  (bf16 out)   [256 blocks]
  gemm8p128<<<(MROWS / 256) * (DMODEL / 128), 512, GLDSPN, stream>>>(
      ffbb, w2b, b2, nullptr, hb, nullptr, y2b, nullptr,
      MROWS, DMODEL, DFF, 0);
  // 8. out = LN2(y2b)  (bf16 in, f32 out)
  ln_kernel<<<MROWS, 256, 0, stream>>>(nullptr, y2b, g2, beta2, out, nullptr);
}